// Round 3
// baseline (5785.623 us; speedup 1.0000x reference)
//
#include <hip/hip_runtime.h>
#include <hip/hip_bf16.h>
#include <cstdint>
#include <cstddef>

#define NEc 16
#define SSc 16
#define BBc 256
#define INc 61
#define HHc 1024
#define LLc 512
#define H3c 3072
#define NEBc 4096   // NE*B
#define KXc 64      // x width padded 61->64
#define HB  16      // h-blocks of 64

typedef __hip_bfloat16 bf16;
typedef __attribute__((ext_vector_type(8))) short bf16x8;   // 8 bf16 = 4 VGPR (MFMA A/B frag)
typedef __attribute__((ext_vector_type(4))) float f32x4;    // MFMA C/D frag
typedef __attribute__((ext_vector_type(4))) short s16x4;    // 4 bf16 packed store

__device__ __forceinline__ void gload16(const void* g, void* l){
    __builtin_amdgcn_global_load_lds((const __attribute__((address_space(1))) unsigned int*)g,
                                     (__attribute__((address_space(3))) unsigned int*)l, 16, 0, 0);
}

__device__ __forceinline__ float sigmoidf_(float x){ return 1.0f/(1.0f+__expf(-x)); }

// ---------------------------------------------------------------------------
// Fused GRU cell kernel. Block = (hb, row-tile of 64). Computes for its 64
// rows x 64 h-cols: r,z over K1+1024, i_n over K1, h_n over 1024, then the
// full gate update in-register. Virtual col layout per hb: [r 0-63][z 64-127]
// [in 128-191][hn 192-255]; B rows 0..191 = (r,z,n) packed weights.
// Waves 2x2: wm = row half (32 rows), wc = col half (cg0: r+z, cg1: in+hn).
// pre (optional, fp32 [M][3072] packed): adds to r/z/in pre-activations.
// bp fp32 [HB][256]: [bih_r+bhh_r][bih_z+bhh_z][bih_n][bhh_n].
// h fp32 [M][1024] in/out (each elem touched by exactly one block);
// A2 = h_old bf16 shadow (read-only!), hbout = NEW bf16 shadow (ping-pong).
// ---------------------------------------------------------------------------
__global__ __launch_bounds__(256)
void gru_fused(const bf16* __restrict__ A1, int lda1, int K1,
               const bf16* __restrict__ Wlo,   // [HB][192][K1] or null (K1==0)
               const bf16* __restrict__ A2,    // [M][1024]
               const bf16* __restrict__ Whi,   // [HB][192][1024]
               const float* __restrict__ pre,  // [M][3072] packed or null
               const float* __restrict__ bp,   // [HB][256]
               float* __restrict__ h,          // [M][1024]
               bf16* __restrict__ hbout,       // [M][1024]
               bf16* __restrict__ out2)        // optional [M][1024]
{
    __shared__ char smem[64*128 + 192*128];    // sA (8KB) | sB (24KB)
    char* sA = smem;
    char* sB = smem + 64*128;

    const int tid  = threadIdx.x;
    const int lane = tid & 63;
    const int wave = tid >> 6;
    const int wm   = wave >> 1;       // row half
    const int wc   = wave & 1;        // col half (0: r+z, 1: in+hn)
    const int lr   = lane & 15;
    const int lk   = lane >> 4;
    const int hb   = blockIdx.x;
    const int m0   = blockIdx.y * 64;

    const bf16* WloB = Wlo ? (Wlo + (size_t)hb*192*K1) : Wlo;
    const bf16* WhiB = Whi + (size_t)hb*192*1024;

    f32x4 acc[2][8];
    #pragma unroll
    for (int mi=0;mi<2;mi++)
      #pragma unroll
      for (int ni=0;ni<8;ni++)
        #pragma unroll
        for (int j=0;j<4;j++) acc[mi][ni][j] = 0.f;

    bool first = true;
    for (int ph=0; ph<2; ++ph){
        const bf16* Ab = ph ? A2 : A1;
        const bf16* Bb = ph ? WhiB : WloB;
        const int lda  = ph ? 1024 : lda1;
        const int ldb  = ph ? 1024 : K1;
        const int Kp   = ph ? 1024 : K1;
        for (int k0 = 0; k0 < Kp; k0 += 64){
            if (!first) __syncthreads();
            first = false;
            #pragma unroll
            for (int i=0;i<2;i++){                    // A tile: 64 rows
                const int o = i*4096 + tid*16;
                const int u = o ^ (((o>>7)&7)<<4);
                gload16(Ab + (size_t)(m0 + (u>>7))*lda + k0 + ((u&127)>>1), sA + o);
            }
            #pragma unroll
            for (int i=0;i<6;i++){                    // B tile: 192 rows
                const int o = i*4096 + tid*16;
                const int u = o ^ (((o>>7)&7)<<4);
                gload16(Bb + (size_t)(u>>7)*ldb + k0 + ((u&127)>>1), sB + o);
            }
            __syncthreads();
            #pragma unroll
            for (int ks=0;ks<2;ks++){
                bf16x8 av[2];
                #pragma unroll
                for (int mi=0;mi<2;mi++){
                    const int r = wm*32 + mi*16 + lr;
                    const int u = r*128 + ks*64 + lk*16;
                    av[mi] = *(const bf16x8*)(sA + (u ^ ((r&7)<<4)));
                }
                #pragma unroll
                for (int ni=0;ni<8;ni++){
                    if (wc==1 && (ni>>2)!=ph) continue;   // cg1: 'in' in ph0, 'hn' in ph1
                    const int br = (wc ? 128 + (ni&3)*16 : ni*16) + lr;
                    const int u  = br*128 + ks*64 + lk*16;
                    const bf16x8 bv = *(const bf16x8*)(sB + (u ^ ((br&7)<<4)));
                    #pragma unroll
                    for (int mi=0;mi<2;mi++)
                        acc[mi][ni] = __builtin_amdgcn_mfma_f32_16x16x32_bf16(av[mi], bv, acc[mi][ni], 0,0,0);
                }
            }
        }
    }

    __syncthreads();                 // all MFMA ds_reads done; reuse LDS
    float* rz = (float*)smem;        // [64][128]: r | z

    if (wc==0){
        #pragma unroll
        for (int mi=0;mi<2;mi++)
          #pragma unroll
          for (int ni=0;ni<8;ni++)
            #pragma unroll
            for (int j=0;j<4;j++){
                const int rl = wm*32 + mi*16 + lk*4 + j;   // C/D: row=(lane>>4)*4+j
                const int vc = ni*16 + lr;                 //      col=lane&15
                float v = acc[mi][ni][j] + bp[hb*256 + vc];
                if (pre) v += pre[(size_t)(m0+rl)*H3c + hb*192 + vc];
                rz[rl*128 + vc] = sigmoidf_(v);
            }
    }
    __syncthreads();
    if (wc==1){
        #pragma unroll
        for (int mi=0;mi<2;mi++)
          #pragma unroll
          for (int ni=0;ni<4;ni++)
            #pragma unroll
            for (int j=0;j<4;j++){
                const int rl = wm*32 + mi*16 + lk*4 + j;
                const int m  = m0 + rl;
                const int hc = ni*16 + lr;
                float vin = acc[mi][ni][j] + bp[hb*256 + 128 + hc];
                if (pre) vin += pre[(size_t)m*H3c + hb*192 + 128 + hc];
                const float vhn = acc[mi][ni+4][j] + bp[hb*256 + 192 + hc];
                const float rr = rz[rl*128 + hc];
                const float zz = rz[rl*128 + 64 + hc];
                const float n  = tanhf(vin + rr*vhn);
                const size_t off = (size_t)m*HHc + hb*64 + hc;
                const float hold = h[off];
                const float hnew = (1.f - zz)*n + zz*hold;
                h[off] = hnew;
                hbout[off] = __float2bfloat16(hnew);
                if (out2) out2[off] = __float2bfloat16(hnew);
            }
    }
}

// ---------------------------------------------------------------------------
// Packed-output GEMM: C[m][hb*192 + c] = A[m] . Ep[hb][c], K=512.
// Used for gi0c (latent@c_wih0 packed) and giE (emb@We packed).
// ---------------------------------------------------------------------------
__global__ __launch_bounds__(256)
void gemm_pack(const bf16* __restrict__ A,   // [M][512]
               const bf16* __restrict__ Ep,  // [HB][192][512]
               float* __restrict__ C)        // [M][3072]
{
    __shared__ char smem[64*128 + 192*128];
    char* sA = smem;
    char* sB = smem + 64*128;
    const int tid  = threadIdx.x;
    const int lane = tid & 63;
    const int wave = tid >> 6;
    const int wm   = wave >> 1;
    const int wc   = wave & 1;
    const int lr   = lane & 15;
    const int lk   = lane >> 4;
    const int hb   = blockIdx.x;
    const int m0   = blockIdx.y * 64;
    const bf16* Bb = Ep + (size_t)hb*192*512;

    f32x4 acc[2][6];
    #pragma unroll
    for (int mi=0;mi<2;mi++)
      #pragma unroll
      for (int ni=0;ni<6;ni++)
        #pragma unroll
        for (int j=0;j<4;j++) acc[mi][ni][j] = 0.f;

    for (int k0 = 0; k0 < 512; k0 += 64){
        if (k0) __syncthreads();
        #pragma unroll
        for (int i=0;i<2;i++){
            const int o = i*4096 + tid*16;
            const int u = o ^ (((o>>7)&7)<<4);
            gload16(A + (size_t)(m0 + (u>>7))*512 + k0 + ((u&127)>>1), sA + o);
        }
        #pragma unroll
        for (int i=0;i<6;i++){
            const int o = i*4096 + tid*16;
            const int u = o ^ (((o>>7)&7)<<4);
            gload16(Bb + (size_t)(u>>7)*512 + k0 + ((u&127)>>1), sB + o);
        }
        __syncthreads();
        #pragma unroll
        for (int ks=0;ks<2;ks++){
            bf16x8 av[2];
            #pragma unroll
            for (int mi=0;mi<2;mi++){
                const int r = wm*32 + mi*16 + lr;
                const int u = r*128 + ks*64 + lk*16;
                av[mi] = *(const bf16x8*)(sA + (u ^ ((r&7)<<4)));
            }
            #pragma unroll
            for (int ni=0;ni<6;ni++){
                const int br = wc*96 + ni*16 + lr;
                const int u  = br*128 + ks*64 + lk*16;
                const bf16x8 bv = *(const bf16x8*)(sB + (u ^ ((br&7)<<4)));
                #pragma unroll
                for (int mi=0;mi<2;mi++)
                    acc[mi][ni] = __builtin_amdgcn_mfma_f32_16x16x32_bf16(av[mi], bv, acc[mi][ni], 0,0,0);
            }
        }
    }
    #pragma unroll
    for (int mi=0;mi<2;mi++)
      #pragma unroll
      for (int ni=0;ni<6;ni++)
        #pragma unroll
        for (int j=0;j<4;j++){
            const int rl = wm*32 + mi*16 + lk*4 + j;
            const int vc = wc*96 + ni*16 + lr;
            C[(size_t)(m0+rl)*H3c + hb*192 + vc] = acc[mi][ni][j];
        }
}

// ---------------------------------------------------------------------------
// plain bf16 GEMM-NT (from R2, verified): C[M,N] = A[M,K] @ B[N,K]^T, C fp32
// ---------------------------------------------------------------------------
template<int BM,int BN>
__global__ __launch_bounds__(256)
void gemm_bf(const bf16* __restrict__ A, const bf16* __restrict__ Bm, float* __restrict__ C,
             int K, int ldc)
{
    constexpr int WAVES_M = (BM==128) ? 2 : 1;
    constexpr int WM = BM / WAVES_M;
    constexpr int WN = BN / (4/WAVES_M);
    constexpr int MR = WM / 16;
    constexpr int NR = WN / 16;
    constexpr int ASW = (BM*128)/4096;
    constexpr int BSW = (BN*128)/4096;

    __shared__ char smem[(BM+BN)*128];
    char* sA = smem;
    char* sB = smem + BM*128;

    const int tid  = threadIdx.x;
    const int lane = tid & 63;
    const int wave = tid >> 6;
    const int wm   = (WAVES_M==2) ? (wave>>1) : 0;
    const int wn   = (WAVES_M==2) ? (wave&1)  : wave;
    const int lr   = lane & 15;
    const int lk   = lane >> 4;
    const int m0   = blockIdx.y * BM;
    const int n0   = blockIdx.x * BN;

    f32x4 acc[MR][NR];
    #pragma unroll
    for (int mi=0;mi<MR;mi++)
      #pragma unroll
      for (int ni=0;ni<NR;ni++)
        #pragma unroll
        for (int j=0;j<4;j++) acc[mi][ni][j] = 0.f;

    for (int k0 = 0; k0 < K; k0 += 64){
        if (k0) __syncthreads();
        #pragma unroll
        for (int i=0;i<ASW;i++){
            const int o = i*4096 + tid*16;
            const int u = o ^ (((o>>7)&7)<<4);
            gload16(A + (size_t)(m0 + (u>>7))*K + k0 + ((u&127)>>1), sA + o);
        }
        #pragma unroll
        for (int i=0;i<BSW;i++){
            const int o = i*4096 + tid*16;
            const int u = o ^ (((o>>7)&7)<<4);
            gload16(Bm + (size_t)(n0 + (u>>7))*K + k0 + ((u&127)>>1), sB + o);
        }
        __syncthreads();
        #pragma unroll
        for (int ks=0;ks<2;ks++){
            bf16x8 av[MR], bv[NR];
            #pragma unroll
            for (int mi=0;mi<MR;mi++){
                const int r = wm*WM + mi*16 + lr;
                const int u = r*128 + ks*64 + lk*16;
                av[mi] = *(const bf16x8*)(sA + (u ^ ((r&7)<<4)));
            }
            #pragma unroll
            for (int ni=0;ni<NR;ni++){
                const int r = wn*WN + ni*16 + lr;
                const int u = r*128 + ks*64 + lk*16;
                bv[ni] = *(const bf16x8*)(sB + (u ^ ((r&7)<<4)));
            }
            #pragma unroll
            for (int mi=0;mi<MR;mi++)
              #pragma unroll
              for (int ni=0;ni<NR;ni++)
                acc[mi][ni] = __builtin_amdgcn_mfma_f32_16x16x32_bf16(av[mi], bv[ni], acc[mi][ni], 0,0,0);
        }
    }
    #pragma unroll
    for (int mi=0;mi<MR;mi++)
      #pragma unroll
      for (int ni=0;ni<NR;ni++)
        #pragma unroll
        for (int j=0;j<4;j++){
            const int r = m0 + wm*WM + mi*16 + lk*4 + j;
            const int c = n0 + wn*WN + ni*16 + lr;
            C[(size_t)r*ldc + c] = acc[mi][ni][j];
        }
}

// ---------------------------------------------------------------------------
// setup kernels
// ---------------------------------------------------------------------------
// pack GRU weights: dst[hb][c][k] bf16; c in [0,192): g=c>>6, i=hb*64+(c&63),
// src row g*1024+i, src col col0+k (valid k<Kvalid, else 0), row stride srcld.
__global__ __launch_bounds__(256) void pack_w(const float* __restrict__ src, int srcld,
                                              int col0, int Kvalid, int Kpad,
                                              bf16* __restrict__ dst, int total){
    const int idx = blockIdx.x*256 + threadIdx.x;
    if (idx >= total) return;
    const int k  = idx % Kpad;
    const int c  = (idx / Kpad) % 192;
    const int hb = idx / (Kpad*192);
    const int i  = hb*64 + (c&63);
    const int g  = c >> 6;
    const float v = (k < Kvalid) ? src[(size_t)(g*HHc + i)*srcld + col0 + k] : 0.f;
    dst[idx] = __float2bfloat16(v);
}

// bp[hb][256] = [bih_r+bhh_r][bih_z+bhh_z][bih_n][bhh_n]
__global__ __launch_bounds__(256) void pack_bias(const float* __restrict__ bih,
                                                 const float* __restrict__ bhh,
                                                 float* __restrict__ bp){
    const int idx = blockIdx.x*256 + threadIdx.x;
    if (idx >= HB*256) return;
    const int c  = idx & 255;
    const int hb = idx >> 8;
    const int i  = hb*64 + (c&63);
    const int g  = c >> 6;
    float v;
    if      (g==0) v = bih[i] + bhh[i];
    else if (g==1) v = bih[HHc+i] + bhh[HHc+i];
    else if (g==2) v = bih[2*HHc+i];
    else           v = bhh[2*HHc+i];
    bp[idx] = v;
}

__global__ __launch_bounds__(256) void cvt_bf16_k(const float* __restrict__ in, bf16* __restrict__ out, int n4){
    const int i = blockIdx.x*256 + threadIdx.x;
    if (i >= n4) return;
    const f32x4 v = *(const f32x4*)(in + (size_t)i*4);
    union { s16x4 s; bf16 b[4]; } u;
    #pragma unroll
    for (int j=0;j<4;j++) u.b[j] = __float2bfloat16(v[j]);
    *(s16x4*)(out + (size_t)i*4) = u.s;
}

// o_w [61][1024] -> owb [64][1024] zero-padded rows
__global__ __launch_bounds__(256) void pad_ow(const float* __restrict__ w, bf16* __restrict__ o){
    const int idx = blockIdx.x*256 + threadIdx.x;
    if (idx >= KXc*HHc) return;
    const int r = idx >> 10;
    o[idx] = __float2bfloat16(r < INc ? w[(size_t)r*HHc + (idx & (HHc-1))] : 0.f);
}

// target [NE*S][B][61] -> xb bf16 [S][NE*B][64] zero-padded
__global__ __launch_bounds__(256) void build_xb(const float* __restrict__ t, bf16* __restrict__ xb){
    const int idx = blockIdx.x*256 + threadIdx.x;
    if (idx >= SSc*NEBc*KXc) return;
    const int c  = idx & 63;
    const int rr = idx >> 6;
    const int s  = rr >> 12;
    const int r  = rr & 4095;
    const int ne = r >> 8;
    const int b  = r & 255;
    const float v = (c < INc) ? t[(((size_t)(ne*SSc + s)*BBc + b)*INc) + c] : 0.f;
    xb[idx] = __float2bfloat16(v);
}

// h0 [2][256][1024] -> h0c/h1c fp32 + bf16 shadows
__global__ __launch_bounds__(256) void init_hc(const float* __restrict__ h0,
                                               float* __restrict__ h0c, float* __restrict__ h1c,
                                               bf16* __restrict__ h0cb, bf16* __restrict__ h1cb){
    const int i = blockIdx.x*256 + threadIdx.x;
    if (i >= (BBc*HHc)/4) return;
    const int e = i*4;
    f32x4 a = *(const f32x4*)(h0 + e);
    f32x4 b = *(const f32x4*)(h0 + BBc*HHc + e);
    union { s16x4 v; bf16 q[4]; } ua, ub;
    #pragma unroll
    for (int j=0;j<4;j++){ ua.q[j]=__float2bfloat16(a[j]); ub.q[j]=__float2bfloat16(b[j]); }
    *(f32x4*)(h0c + e) = a; *(f32x4*)(h1c + e) = b;
    *(s16x4*)(h0cb + e) = ua.v; *(s16x4*)(h1cb + e) = ub.v;
}

// h0_dec [NE][2][256][1024] -> hd0/hd1 [NE*B][H] fp32 + bf16
__global__ __launch_bounds__(256) void init_hd(const float* __restrict__ hd,
                                               float* __restrict__ hd0, float* __restrict__ hd1,
                                               bf16* __restrict__ hd0b, bf16* __restrict__ hd1b){
    const int i = blockIdx.x*256 + threadIdx.x;
    if (i >= (NEBc*HHc)/4) return;
    const int e  = i*4;
    const int hh = e & (HHc-1);
    const int r  = e >> 10;
    const int ne = r >> 8;
    const int b  = r & 255;
    f32x4 a = *(const f32x4*)(hd + (((size_t)ne*2 + 0)*BBc + b)*HHc + hh);
    f32x4 c = *(const f32x4*)(hd + (((size_t)ne*2 + 1)*BBc + b)*HHc + hh);
    union { s16x4 v; bf16 q[4]; } ua, uc;
    #pragma unroll
    for (int j=0;j<4;j++){ ua.q[j]=__float2bfloat16(a[j]); uc.q[j]=__float2bfloat16(c[j]); }
    *(f32x4*)(hd0 + e) = a; *(f32x4*)(hd1 + e) = c;
    *(s16x4*)(hd0b + e) = ua.v; *(s16x4*)(hd1b + e) = uc.v;
}

__global__ __launch_bounds__(256) void bias_tanh4(const float* __restrict__ in,
                                                  const float* __restrict__ b, bf16* __restrict__ out){
    const int i = blockIdx.x*256 + threadIdx.x;
    if (i >= (NEBc*LLc)/4) return;
    const int e = i*4;
    const int c = e & (LLc-1);
    f32x4 v = *(const f32x4*)(in + e);
    f32x4 bb = *(const f32x4*)(b + c);
    union { s16x4 s; bf16 q[4]; } u;
    #pragma unroll
    for (int j=0;j<4;j++) u.q[j] = __float2bfloat16(tanhf(v[j] + bb[j]));
    *(s16x4*)(out + e) = u.s;
}

__global__ __launch_bounds__(256) void softmax_out(const float* __restrict__ logits,
                                                   const float* __restrict__ ob,
                                                   float* __restrict__ out, int t)
{
    const int r    = blockIdx.x*4 + (threadIdx.x >> 6);
    const int lane = threadIdx.x & 63;
    float v = -1e30f;
    if (lane < INc) v = logits[(size_t)r*KXc + lane] + ob[lane];
    float m = v;
    #pragma unroll
    for (int o=32;o>0;o>>=1) m = fmaxf(m, __shfl_xor(m, o));
    float e = (lane < INc) ? __expf(v - m) : 0.f;
    float s = e;
    #pragma unroll
    for (int o=32;o>0;o>>=1) s += __shfl_xor(s, o);
    if (lane < INc){
        const int ne = r >> 8, b = r & 255;
        out[((size_t)((ne*SSc + t)*BBc + b))*INc + lane] = e / s;
    }
}

// ---------------- host side ----------------

extern "C" void kernel_launch(void* const* d_in, const int* in_sizes, int n_in,
                              void* d_out, int out_size, void* d_ws, size_t ws_size,
                              hipStream_t stream)
{
    const float* target = (const float*)d_in[0];
    const float* latent = (const float*)d_in[1];
    const float* h0     = (const float*)d_in[2];
    const float* h0_dec = (const float*)d_in[3];
    const float* c_wih0 = (const float*)d_in[4];
    const float* c_whh0 = (const float*)d_in[5];
    const float* c_bih0 = (const float*)d_in[6];
    const float* c_bhh0 = (const float*)d_in[7];
    const float* c_wih1 = (const float*)d_in[8];
    const float* c_whh1 = (const float*)d_in[9];
    const float* c_bih1 = (const float*)d_in[10];
    const float* c_bhh1 = (const float*)d_in[11];
    const float* ce_w   = (const float*)d_in[12];
    const float* ce_b   = (const float*)d_in[13];
    const float* d_wih0 = (const float*)d_in[14];
    const float* d_whh0 = (const float*)d_in[15];
    const float* d_bih0 = (const float*)d_in[16];
    const float* d_bhh0 = (const float*)d_in[17];
    const float* d_wih1 = (const float*)d_in[18];
    const float* d_whh1 = (const float*)d_in[19];
    const float* d_bih1 = (const float*)d_in[20];
    const float* d_bhh1 = (const float*)d_in[21];
    const float* o_w    = (const float*)d_in[22];
    const float* o_b    = (const float*)d_in[23];
    float* out = (float*)d_out;

    // ---- workspace (fp32 pool, then bf16 pool) ----
    float* fp = (float*)d_ws;
    auto fa = [&](size_t n){ float* q = fp; fp += n; return q; };
    float* giE   = fa((size_t)NEBc*H3c);   // packed giE fp32
    float* gi0c  = fa((size_t)BBc*H3c);    // packed conductor-l0 gi fp32
    float* hd0   = fa((size_t)NEBc*HHc);
    float* hd1   = fa((size_t)NEBc*HHc);
    float* h0c   = fa((size_t)BBc*HHc);
    float* h1c   = fa((size_t)BBc*HHc);
    float* emb   = fa((size_t)NEBc*LLc);
    float* logits= fa((size_t)NEBc*KXc);
    float* bp_c0 = fa(HB*256);
    float* bp_c1 = fa(HB*256);
    float* bp_d0 = fa(HB*256);
    float* bp_d1 = fa(HB*256);

    bf16* bb = (bf16*)fp;
    auto ba = [&](size_t n){ bf16* q = bb; bb += n; return q; };
    bf16* hd0b[2] = { ba((size_t)NEBc*HHc), ba((size_t)NEBc*HHc) };
    bf16* hd1b[2] = { ba((size_t)NEBc*HHc), ba((size_t)NEBc*HHc) };
    bf16* h0cb[2] = { ba((size_t)BBc*HHc),  ba((size_t)BBc*HHc) };
    bf16* h1cb[2] = { ba((size_t)BBc*HHc),  ba((size_t)BBc*HHc) };
    bf16* xb    = ba((size_t)SSc*NEBc*KXc);
    bf16* coutb = ba((size_t)NEBc*HHc);
    bf16* embb  = ba((size_t)NEBc*LLc);
    bf16* latb  = ba((size_t)BBc*LLc);
    bf16* Wlo_d0= ba((size_t)HB*192*KXc);
    bf16* Whi_d0= ba((size_t)HB*192*HHc);
    bf16* Wlo_d1= ba((size_t)HB*192*HHc);
    bf16* Whi_d1= ba((size_t)HB*192*HHc);
    bf16* Whi_c0= ba((size_t)HB*192*HHc);
    bf16* Wlo_c1= ba((size_t)HB*192*HHc);
    bf16* Whi_c1= ba((size_t)HB*192*HHc);
    bf16* Epd   = ba((size_t)HB*192*LLc);
    bf16* Epc   = ba((size_t)HB*192*LLc);
    bf16* cewb  = ba((size_t)LLc*HHc);
    bf16* owb   = ba((size_t)KXc*HHc);

    auto packw = [&](const float* src, int ld, int c0, int kv, int kp, bf16* dst){
        const int tot = HB*192*kp;
        hipLaunchKernelGGL(pack_w, dim3((tot+255)/256), dim3(256),0,stream, src,ld,c0,kv,kp,dst,tot);
    };

    // ---- setup ----
    hipLaunchKernelGGL(cvt_bf16_k, dim3((BBc*LLc/4+255)/256), dim3(256),0,stream, latent, latb, BBc*LLc/4);
    hipLaunchKernelGGL(cvt_bf16_k, dim3((LLc*HHc/4+255)/256), dim3(256),0,stream, ce_w, cewb, LLc*HHc/4);
    hipLaunchKernelGGL(pad_ow, dim3((KXc*HHc)/256), dim3(256),0,stream, o_w, owb);
    hipLaunchKernelGGL(build_xb, dim3((SSc*NEBc*KXc)/256), dim3(256),0,stream, target, xb);
    hipLaunchKernelGGL(init_hc, dim3((BBc*HHc/4)/256), dim3(256),0,stream, h0, h0c, h1c, h0cb[0], h1cb[0]);
    hipLaunchKernelGGL(init_hd, dim3((NEBc*HHc/4)/256), dim3(256),0,stream, h0_dec, hd0, hd1, hd0b[0], hd1b[0]);
    packw(d_wih0, INc+LLc, 0,   INc, KXc, Wlo_d0);
    packw(d_whh0, HHc,     0, HHc, HHc, Whi_d0);
    packw(d_wih1, HHc,     0, HHc, HHc, Wlo_d1);
    packw(d_whh1, HHc,     0, HHc, HHc, Whi_d1);
    packw(c_whh0, HHc,     0, HHc, HHc, Whi_c0);
    packw(c_wih1, HHc,     0, HHc, HHc, Wlo_c1);
    packw(c_whh1, HHc,     0, HHc, HHc, Whi_c1);
    packw(d_wih0, INc+LLc, INc, LLc, LLc, Epd);
    packw(c_wih0, LLc,     0, LLc, LLc, Epc);
    hipLaunchKernelGGL(pack_bias, dim3((HB*256+255)/256), dim3(256),0,stream, c_bih0, c_bhh0, bp_c0);
    hipLaunchKernelGGL(pack_bias, dim3((HB*256+255)/256), dim3(256),0,stream, c_bih1, c_bhh1, bp_c1);
    hipLaunchKernelGGL(pack_bias, dim3((HB*256+255)/256), dim3(256),0,stream, d_bih0, d_bhh0, bp_d0);
    hipLaunchKernelGGL(pack_bias, dim3((HB*256+255)/256), dim3(256),0,stream, d_bih1, d_bhh1, bp_d1);

    // conductor l0 gi (loop-invariant), packed layout
    hipLaunchKernelGGL(gemm_pack, dim3(HB, BBc/64), dim3(256),0,stream, latb, Epc, gi0c);

    // ---- conductor: 16 sequential 2-layer fused GRU steps (M=256) ----
    int c = 0;
    for (int s=0;s<NEc;s++){
        hipLaunchKernelGGL(gru_fused, dim3(HB, BBc/64), dim3(256),0,stream,
                           (const bf16*)nullptr, 0, 0, (const bf16*)nullptr,
                           h0cb[c], Whi_c0, gi0c, bp_c0, h0c, h0cb[1-c], (bf16*)nullptr);
        hipLaunchKernelGGL(gru_fused, dim3(HB, BBc/64), dim3(256),0,stream,
                           h0cb[1-c], HHc, HHc, Wlo_c1,
                           h1cb[c], Whi_c1, (const float*)nullptr, bp_c1, h1c, h1cb[1-c],
                           coutb + (size_t)s*BBc*HHc);
        c ^= 1;
    }

    // ---- embedding: emb = tanh(cout @ ce_w^T + b); then packed giE = emb @ We^T ----
    hipLaunchKernelGGL((gemm_bf<128,128>), dim3(LLc/128, NEBc/128), dim3(256),0,stream,
                       coutb, cewb, emb, HHc, LLc);
    hipLaunchKernelGGL(bias_tanh4, dim3((NEBc*LLc/4)/256), dim3(256),0,stream, emb, ce_b, embb);
    hipLaunchKernelGGL(gemm_pack, dim3(HB, NEBc/64), dim3(256),0,stream, embb, Epd, giE);

    // ---- decoder: 16 sequential 2-layer fused GRU steps (M=4096) ----
    int d = 0;
    for (int t=0;t<SSc;t++){
        hipLaunchKernelGGL(gru_fused, dim3(HB, NEBc/64), dim3(256),0,stream,
                           xb + (size_t)t*NEBc*KXc, KXc, KXc, Wlo_d0,
                           hd0b[d], Whi_d0, giE, bp_d0, hd0, hd0b[1-d], (bf16*)nullptr);
        hipLaunchKernelGGL(gru_fused, dim3(HB, NEBc/64), dim3(256),0,stream,
                           hd0b[1-d], HHc, HHc, Wlo_d1,
                           hd1b[d], Whi_d1, (const float*)nullptr, bp_d1, hd1, hd1b[1-d], (bf16*)nullptr);
        hipLaunchKernelGGL((gemm_bf<64,64>), dim3(KXc/64, NEBc/64), dim3(256),0,stream,
                           hd1b[1-d], owb, logits, HHc, KXc);
        hipLaunchKernelGGL(softmax_out, dim3(NEBc/4), dim3(256),0,stream, logits, o_b, out, t);
        d ^= 1;
    }
}

// Round 4
// 4753.288 us; speedup vs baseline: 1.2172x; 1.2172x over previous
//
#include <hip/hip_runtime.h>
#include <hip/hip_bf16.h>
#include <cstdint>
#include <cstddef>

#define NEc 16
#define SSc 16
#define BBc 256
#define INc 61
#define HHc 1024
#define LLc 512
#define H3c 3072
#define NEBc 4096   // NE*B
#define KXc 64      // x width padded 61->64
#define HB  16      // h-blocks of 64

typedef __hip_bfloat16 bf16;
typedef __attribute__((ext_vector_type(8))) short bf16x8;   // 8 bf16 = 4 VGPR (MFMA A/B frag)
typedef __attribute__((ext_vector_type(4))) float f32x4;    // MFMA C/D frag
typedef __attribute__((ext_vector_type(4))) short s16x4;    // 4 bf16 packed store

__device__ __forceinline__ void gload16(const void* g, void* l){
    __builtin_amdgcn_global_load_lds((const __attribute__((address_space(1))) unsigned int*)g,
                                     (__attribute__((address_space(3))) unsigned int*)l, 16, 0, 0);
}

__device__ __forceinline__ float sigmoidf_(float x){ return 1.0f/(1.0f+__expf(-x)); }

// ---------------------------------------------------------------------------
// Balanced fused GRU cell. Packed weight layout per hb (64 h-cols):
// 192 B-rows, row c: g=c>>4, hsub=g/3, gate=g%3 (r,z,n), h-col=hb*64+hsub*16+(c&15).
// Wave (wm,wc): wm = row half, wc = h-col half (hsub pair). Each wave computes
// r,z,in,hn fragments for ITS OWN h-cols -> same lane holds all four gates of
// one h element -> pure-register epilogue, zero LDS exchange, balanced MFMAs.
// Phase0: A1[M][K1] x Wlo (gi: r,z,in). Phase1: A2[M][1024] x Whi (gh: r,z,hn).
// pre: optional bf16 [M][3072] in packed col layout, added to r,z,in.
// bp fp32 [HB][256]: [bih_r+bhh_r][bih_z+bhh_z][bih_n][bhh_n].
// ---------------------------------------------------------------------------
template<int BM>
__global__ __launch_bounds__(256)
void gru_fused2(const bf16* __restrict__ A1, int lda1, int K1,
                const bf16* __restrict__ Wlo,   // [HB][192][K1] or null
                const bf16* __restrict__ A2,    // [M][1024] h_old bf16 (read-only)
                const bf16* __restrict__ Whi,   // [HB][192][1024]
                const bf16* __restrict__ pre,   // [M][3072] packed bf16 or null
                const float* __restrict__ bp,   // [HB][256]
                float* __restrict__ h,          // [M][1024] in/out
                bf16* __restrict__ hbout,       // [M][1024] new bf16 shadow
                bf16* __restrict__ out2)        // optional extra bf16 copy
{
    constexpr int MR = BM/32;                   // 16-row frags per wave
    __shared__ char smem[(BM+192)*128];
    char* sA = smem;
    char* sB = smem + BM*128;

    const int tid  = threadIdx.x;
    const int lane = tid & 63;
    const int wave = tid >> 6;
    const int wm   = wave >> 1;
    const int wc   = wave & 1;
    const int lr   = lane & 15;
    const int lk   = lane >> 4;
    const int hb   = blockIdx.x;
    const int m0   = blockIdx.y * BM;

    const bf16* WloB = Wlo ? (Wlo + (size_t)hb*192*K1) : Wlo;
    const bf16* WhiB = Whi + (size_t)hb*192*1024;

    f32x4 acc[MR][2][4];                        // [mi][hsub-local][r,z,in,hn]
    #pragma unroll
    for (int mi=0;mi<MR;mi++)
      #pragma unroll
      for (int hs=0;hs<2;hs++)
        #pragma unroll
        for (int g=0;g<4;g++)
          #pragma unroll
          for (int j=0;j<4;j++) acc[mi][hs][g][j] = 0.f;

    bool first = true;
    for (int ph=0; ph<2; ++ph){
        const bf16* Ab = ph ? A2 : A1;
        const bf16* Bb = ph ? WhiB : WloB;
        const int lda  = ph ? 1024 : lda1;
        const int ldb  = ph ? 1024 : K1;
        const int Kp   = ph ? 1024 : K1;
        for (int k0 = 0; k0 < Kp; k0 += 64){
            if (!first) __syncthreads();
            first = false;
            #pragma unroll
            for (int i=0;i<BM/32;i++){                 // A tile: BM rows x 128B
                const int o = i*4096 + tid*16;
                const int u = o ^ (((o>>7)&7)<<4);
                gload16(Ab + (size_t)(m0 + (u>>7))*lda + k0 + ((u&127)>>1), sA + o);
            }
            #pragma unroll
            for (int i=0;i<6;i++){                     // B tile: 192 rows x 128B
                const int o = i*4096 + tid*16;
                const int u = o ^ (((o>>7)&7)<<4);
                gload16(Bb + (size_t)(u>>7)*ldb + k0 + ((u&127)>>1), sB + o);
            }
            __syncthreads();
            #pragma unroll
            for (int ks=0;ks<2;ks++){
                bf16x8 av[MR];
                #pragma unroll
                for (int mi=0;mi<MR;mi++){
                    const int r = wm*(BM/2) + mi*16 + lr;
                    const int u = r*128 + ks*64 + lk*16;
                    av[mi] = *(const bf16x8*)(sA + (u ^ ((r&7)<<4)));
                }
                #pragma unroll
                for (int hs=0;hs<2;hs++){
                    #pragma unroll
                    for (int g3=0;g3<3;g3++){
                        const int br = ((wc*2+hs)*3 + g3)*16 + lr;
                        const int u  = br*128 + ks*64 + lk*16;
                        const bf16x8 bv = *(const bf16x8*)(sB + (u ^ ((br&7)<<4)));
                        if (g3 < 2){
                            #pragma unroll
                            for (int mi=0;mi<MR;mi++)
                                acc[mi][hs][g3] = __builtin_amdgcn_mfma_f32_16x16x32_bf16(av[mi], bv, acc[mi][hs][g3], 0,0,0);
                        } else if (ph == 0){
                            #pragma unroll
                            for (int mi=0;mi<MR;mi++)
                                acc[mi][hs][2] = __builtin_amdgcn_mfma_f32_16x16x32_bf16(av[mi], bv, acc[mi][hs][2], 0,0,0);
                        } else {
                            #pragma unroll
                            for (int mi=0;mi<MR;mi++)
                                acc[mi][hs][3] = __builtin_amdgcn_mfma_f32_16x16x32_bf16(av[mi], bv, acc[mi][hs][3], 0,0,0);
                        }
                    }
                }
            }
        }
    }

    // ---- pure-register epilogue: full GRU cell, no barriers ----
    #pragma unroll
    for (int hs=0;hs<2;hs++){
        const int hsub = wc*2 + hs;
        const int hc   = hb*64 + hsub*16 + lr;
        const float bpr  = bp[hb*256 +       hsub*16 + lr];
        const float bpz  = bp[hb*256 +  64 + hsub*16 + lr];
        const float bpin = bp[hb*256 + 128 + hsub*16 + lr];
        const float bphn = bp[hb*256 + 192 + hsub*16 + lr];
        #pragma unroll
        for (int mi=0;mi<MR;mi++)
          #pragma unroll
          for (int j=0;j<4;j++){
            const int rl = wm*(BM/2) + mi*16 + lk*4 + j;   // C/D: row=(lane>>4)*4+j
            const int m  = m0 + rl;
            float vr  = acc[mi][hs][0][j] + bpr;
            float vz  = acc[mi][hs][1][j] + bpz;
            float vin = acc[mi][hs][2][j] + bpin;
            const float vhn = acc[mi][hs][3][j] + bphn;
            if (pre){
                const size_t pb = (size_t)m*H3c + hb*192 + hsub*48;
                vr  += __bfloat162float(pre[pb      + lr]);
                vz  += __bfloat162float(pre[pb + 16 + lr]);
                vin += __bfloat162float(pre[pb + 32 + lr]);
            }
            const float r = sigmoidf_(vr);
            const float z = sigmoidf_(vz);
            const float n = tanhf(vin + r*vhn);
            const size_t off = (size_t)m*HHc + hc;
            const float hnew = (1.f - z)*n + z*h[off];
            h[off] = hnew;
            const bf16 hb16 = __float2bfloat16(hnew);
            hbout[off] = hb16;
            if (out2) out2[off] = hb16;
          }
    }
}

// ---------------------------------------------------------------------------
// Packed-output GEMM (K=512): C[m][hb*192+c] = A[m] . Ep[hb][c], bf16 out.
// Used for gi0c (latent@c_wih0 packed) and giE (emb@We packed).
// ---------------------------------------------------------------------------
__global__ __launch_bounds__(256)
void gemm_pack(const bf16* __restrict__ A,   // [M][512]
               const bf16* __restrict__ Ep,  // [HB][192][512] packed rows
               bf16* __restrict__ C)         // [M][3072] packed cols
{
    __shared__ char smem[64*128 + 192*128];
    char* sA = smem;
    char* sB = smem + 64*128;
    const int tid  = threadIdx.x;
    const int lane = tid & 63;
    const int wave = tid >> 6;
    const int wm   = wave >> 1;
    const int wc   = wave & 1;
    const int lr   = lane & 15;
    const int lk   = lane >> 4;
    const int hb   = blockIdx.x;
    const int m0   = blockIdx.y * 64;
    const bf16* Bb = Ep + (size_t)hb*192*512;

    f32x4 acc[2][6];
    #pragma unroll
    for (int mi=0;mi<2;mi++)
      #pragma unroll
      for (int ni=0;ni<6;ni++)
        #pragma unroll
        for (int j=0;j<4;j++) acc[mi][ni][j] = 0.f;

    for (int k0 = 0; k0 < 512; k0 += 64){
        if (k0) __syncthreads();
        #pragma unroll
        for (int i=0;i<2;i++){
            const int o = i*4096 + tid*16;
            const int u = o ^ (((o>>7)&7)<<4);
            gload16(A + (size_t)(m0 + (u>>7))*512 + k0 + ((u&127)>>1), sA + o);
        }
        #pragma unroll
        for (int i=0;i<6;i++){
            const int o = i*4096 + tid*16;
            const int u = o ^ (((o>>7)&7)<<4);
            gload16(Bb + (size_t)(u>>7)*512 + k0 + ((u&127)>>1), sB + o);
        }
        __syncthreads();
        #pragma unroll
        for (int ks=0;ks<2;ks++){
            bf16x8 av[2];
            #pragma unroll
            for (int mi=0;mi<2;mi++){
                const int r = wm*32 + mi*16 + lr;
                const int u = r*128 + ks*64 + lk*16;
                av[mi] = *(const bf16x8*)(sA + (u ^ ((r&7)<<4)));
            }
            #pragma unroll
            for (int ni=0;ni<6;ni++){
                const int br = wc*96 + ni*16 + lr;
                const int u  = br*128 + ks*64 + lk*16;
                const bf16x8 bv = *(const bf16x8*)(sB + (u ^ ((br&7)<<4)));
                #pragma unroll
                for (int mi=0;mi<2;mi++)
                    acc[mi][ni] = __builtin_amdgcn_mfma_f32_16x16x32_bf16(av[mi], bv, acc[mi][ni], 0,0,0);
            }
        }
    }
    #pragma unroll
    for (int mi=0;mi<2;mi++)
      #pragma unroll
      for (int ni=0;ni<6;ni++)
        #pragma unroll
        for (int j=0;j<4;j++){
            const int rl = wm*32 + mi*16 + lk*4 + j;
            const int vc = wc*96 + ni*16 + lr;
            C[(size_t)(m0+rl)*H3c + hb*192 + vc] = __float2bfloat16(acc[mi][ni][j]);
        }
}

// ---------------------------------------------------------------------------
// plain bf16 GEMM-NT (proven): C[M,N] = A[M,K] @ B[N,K]^T, C fp32 (embedding)
// ---------------------------------------------------------------------------
template<int BM,int BN>
__global__ __launch_bounds__(256)
void gemm_bf(const bf16* __restrict__ A, const bf16* __restrict__ Bm, float* __restrict__ C,
             int K, int ldc)
{
    constexpr int WAVES_M = (BM==128) ? 2 : 1;
    constexpr int WM = BM / WAVES_M;
    constexpr int WN = BN / (4/WAVES_M);
    constexpr int MR = WM / 16;
    constexpr int NR = WN / 16;
    constexpr int ASW = (BM*128)/4096;
    constexpr int BSW = (BN*128)/4096;

    __shared__ char smem[(BM+BN)*128];
    char* sA = smem;
    char* sB = smem + BM*128;

    const int tid  = threadIdx.x;
    const int lane = tid & 63;
    const int wave = tid >> 6;
    const int wm   = (WAVES_M==2) ? (wave>>1) : 0;
    const int wn   = (WAVES_M==2) ? (wave&1)  : wave;
    const int lr   = lane & 15;
    const int lk   = lane >> 4;
    const int m0   = blockIdx.y * BM;
    const int n0   = blockIdx.x * BN;

    f32x4 acc[MR][NR];
    #pragma unroll
    for (int mi=0;mi<MR;mi++)
      #pragma unroll
      for (int ni=0;ni<NR;ni++)
        #pragma unroll
        for (int j=0;j<4;j++) acc[mi][ni][j] = 0.f;

    for (int k0 = 0; k0 < K; k0 += 64){
        if (k0) __syncthreads();
        #pragma unroll
        for (int i=0;i<ASW;i++){
            const int o = i*4096 + tid*16;
            const int u = o ^ (((o>>7)&7)<<4);
            gload16(A + (size_t)(m0 + (u>>7))*K + k0 + ((u&127)>>1), sA + o);
        }
        #pragma unroll
        for (int i=0;i<BSW;i++){
            const int o = i*4096 + tid*16;
            const int u = o ^ (((o>>7)&7)<<4);
            gload16(Bm + (size_t)(n0 + (u>>7))*K + k0 + ((u&127)>>1), sB + o);
        }
        __syncthreads();
        #pragma unroll
        for (int ks=0;ks<2;ks++){
            bf16x8 av[MR], bv[NR];
            #pragma unroll
            for (int mi=0;mi<MR;mi++){
                const int r = wm*WM + mi*16 + lr;
                const int u = r*128 + ks*64 + lk*16;
                av[mi] = *(const bf16x8*)(sA + (u ^ ((r&7)<<4)));
            }
            #pragma unroll
            for (int ni=0;ni<NR;ni++){
                const int r = wn*WN + ni*16 + lr;
                const int u = r*128 + ks*64 + lk*16;
                bv[ni] = *(const bf16x8*)(sB + (u ^ ((r&7)<<4)));
            }
            #pragma unroll
            for (int mi=0;mi<MR;mi++)
              #pragma unroll
              for (int ni=0;ni<NR;ni++)
                acc[mi][ni] = __builtin_amdgcn_mfma_f32_16x16x32_bf16(av[mi], bv[ni], acc[mi][ni], 0,0,0);
        }
    }
    #pragma unroll
    for (int mi=0;mi<MR;mi++)
      #pragma unroll
      for (int ni=0;ni<NR;ni++)
        #pragma unroll
        for (int j=0;j<4;j++){
            const int r = m0 + wm*WM + mi*16 + lk*4 + j;
            const int c = n0 + wn*WN + ni*16 + lr;
            C[(size_t)r*ldc + c] = acc[mi][ni][j];
        }
}

// ---------------------------------------------------------------------------
// Fused output projection + softmax: logits = hd1b @ o_w^T + o_b, softmax
// over 61 cols, scatter to out. Block = 64 rows; K=1024 MFMA; LDS softmax.
// ---------------------------------------------------------------------------
__global__ __launch_bounds__(256)
void owsm(const bf16* __restrict__ A,    // [4096][1024]
          const bf16* __restrict__ Bw,   // [64][1024] (rows 61-63 zero)
          const float* __restrict__ ob,
          float* __restrict__ out, int t)
{
    __shared__ char smem[16384];
    __shared__ float lg[64][65];
    char* sA = smem; char* sB = smem + 8192;
    const int tid  = threadIdx.x;
    const int lane = tid & 63;
    const int wave = tid >> 6;
    const int wm   = wave >> 1;
    const int wc   = wave & 1;
    const int lr   = lane & 15;
    const int lk   = lane >> 4;
    const int m0   = blockIdx.x*64;

    f32x4 acc[2][2];
    #pragma unroll
    for (int mi=0;mi<2;mi++)
      #pragma unroll
      for (int ni=0;ni<2;ni++)
        #pragma unroll
        for (int j=0;j<4;j++) acc[mi][ni][j]=0.f;

    for (int k0=0;k0<1024;k0+=64){
        if (k0) __syncthreads();
        #pragma unroll
        for (int i=0;i<2;i++){
            const int o = i*4096 + tid*16;
            const int u = o ^ (((o>>7)&7)<<4);
            gload16(A + (size_t)(m0 + (u>>7))*1024 + k0 + ((u&127)>>1), sA + o);
        }
        #pragma unroll
        for (int i=0;i<2;i++){
            const int o = i*4096 + tid*16;
            const int u = o ^ (((o>>7)&7)<<4);
            gload16(Bw + (size_t)(u>>7)*1024 + k0 + ((u&127)>>1), sB + o);
        }
        __syncthreads();
        #pragma unroll
        for (int ks=0;ks<2;ks++){
            bf16x8 av[2], bv[2];
            #pragma unroll
            for (int mi=0;mi<2;mi++){
                const int r = wm*32 + mi*16 + lr;
                const int u = r*128 + ks*64 + lk*16;
                av[mi] = *(const bf16x8*)(sA + (u ^ ((r&7)<<4)));
            }
            #pragma unroll
            for (int ni=0;ni<2;ni++){
                const int r = wc*32 + ni*16 + lr;
                const int u = r*128 + ks*64 + lk*16;
                bv[ni] = *(const bf16x8*)(sB + (u ^ ((r&7)<<4)));
            }
            #pragma unroll
            for (int mi=0;mi<2;mi++)
              #pragma unroll
              for (int ni=0;ni<2;ni++)
                acc[mi][ni] = __builtin_amdgcn_mfma_f32_16x16x32_bf16(av[mi], bv[ni], acc[mi][ni], 0,0,0);
        }
    }
    // logits -> LDS (lg does not alias smem; no barrier needed before writes)
    #pragma unroll
    for (int mi=0;mi<2;mi++)
      #pragma unroll
      for (int ni=0;ni<2;ni++)
        #pragma unroll
        for (int j=0;j<4;j++){
            const int rl = wm*32 + mi*16 + lk*4 + j;
            const int c  = wc*32 + ni*16 + lr;
            lg[rl][c] = (c < INc) ? (acc[mi][ni][j] + ob[c]) : -1e30f;
        }
    __syncthreads();
    // softmax: 4 threads per row (same wave), 16 cols each
    const int row = tid >> 2;
    const int q   = tid & 3;
    float mx = -1e30f;
    #pragma unroll
    for (int i=0;i<16;i++) mx = fmaxf(mx, lg[row][q*16+i]);
    mx = fmaxf(mx, __shfl_xor(mx,1));
    mx = fmaxf(mx, __shfl_xor(mx,2));
    float ev[16];
    float s = 0.f;
    #pragma unroll
    for (int i=0;i<16;i++){ ev[i] = __expf(lg[row][q*16+i] - mx); s += ev[i]; }
    s += __shfl_xor(s,1);
    s += __shfl_xor(s,2);
    const float inv = 1.f/s;
    const int R = m0 + row;
    const int ne = R >> 8, b = R & 255;
    float* op = out + ((size_t)((ne*SSc + t)*BBc + b))*INc;
    #pragma unroll
    for (int i=0;i<16;i++){
        const int c = q*16 + i;
        if (c < INc) op[c] = ev[i]*inv;
    }
}

// ---------------------------------------------------------------------------
// setup kernels
// ---------------------------------------------------------------------------
// gate-interleaved packing: dst[hb][c][k], c: g=c>>4, hsub=g/3, gate=g%3,
// src row = gate*1024 + hb*64 + hsub*16 + (c&15), col = col0+k (0 if k>=Kvalid)
__global__ __launch_bounds__(256) void pack_w2(const float* __restrict__ src, int srcld,
                                               int col0, int Kvalid, int Kpad,
                                               bf16* __restrict__ dst, int total){
    const int idx = blockIdx.x*256 + threadIdx.x;
    if (idx >= total) return;
    const int k  = idx % Kpad;
    const int c  = (idx / Kpad) % 192;
    const int hb = idx / (Kpad*192);
    const int g  = c >> 4;
    const int hsub = g/3;
    const int gate = g - hsub*3;
    const int row = gate*HHc + hb*64 + hsub*16 + (c & 15);
    const float v = (k < Kvalid) ? src[(size_t)row*srcld + col0 + k] : 0.f;
    dst[idx] = __float2bfloat16(v);
}

// bp[hb][256] = [bih_r+bhh_r][bih_z+bhh_z][bih_n][bhh_n], within-64 = h offset
__global__ __launch_bounds__(256) void pack_bias(const float* __restrict__ bih,
                                                 const float* __restrict__ bhh,
                                                 float* __restrict__ bp){
    const int idx = blockIdx.x*256 + threadIdx.x;
    if (idx >= HB*256) return;
    const int c  = idx & 255;
    const int hb = idx >> 8;
    const int i  = hb*64 + (c&63);
    const int g  = c >> 6;
    float v;
    if      (g==0) v = bih[i] + bhh[i];
    else if (g==1) v = bih[HHc+i] + bhh[HHc+i];
    else if (g==2) v = bih[2*HHc+i];
    else           v = bhh[2*HHc+i];
    bp[idx] = v;
}

__global__ __launch_bounds__(256) void cvt_bf16_k(const float* __restrict__ in, bf16* __restrict__ out, int n4){
    const int i = blockIdx.x*256 + threadIdx.x;
    if (i >= n4) return;
    const f32x4 v = *(const f32x4*)(in + (size_t)i*4);
    union { s16x4 s; bf16 b[4]; } u;
    #pragma unroll
    for (int j=0;j<4;j++) u.b[j] = __float2bfloat16(v[j]);
    *(s16x4*)(out + (size_t)i*4) = u.s;
}

// o_w [61][1024] -> owb [64][1024] zero-padded rows
__global__ __launch_bounds__(256) void pad_ow(const float* __restrict__ w, bf16* __restrict__ o){
    const int idx = blockIdx.x*256 + threadIdx.x;
    if (idx >= KXc*HHc) return;
    const int r = idx >> 10;
    o[idx] = __float2bfloat16(r < INc ? w[(size_t)r*HHc + (idx & (HHc-1))] : 0.f);
}

// target [NE*S][B][61] -> xb bf16 [S][NE*B][64] zero-padded
__global__ __launch_bounds__(256) void build_xb(const float* __restrict__ t, bf16* __restrict__ xb){
    const int idx = blockIdx.x*256 + threadIdx.x;
    if (idx >= SSc*NEBc*KXc) return;
    const int c  = idx & 63;
    const int rr = idx >> 6;
    const int s  = rr >> 12;
    const int r  = rr & 4095;
    const int ne = r >> 8;
    const int b  = r & 255;
    const float v = (c < INc) ? t[(((size_t)(ne*SSc + s)*BBc + b)*INc) + c] : 0.f;
    xb[idx] = __float2bfloat16(v);
}

// h0 [2][256][1024] -> h0c/h1c fp32 + bf16 shadows
__global__ __launch_bounds__(256) void init_hc(const float* __restrict__ h0,
                                               float* __restrict__ h0c, float* __restrict__ h1c,
                                               bf16* __restrict__ h0cb, bf16* __restrict__ h1cb){
    const int i = blockIdx.x*256 + threadIdx.x;
    if (i >= (BBc*HHc)/4) return;
    const int e = i*4;
    f32x4 a = *(const f32x4*)(h0 + e);
    f32x4 b = *(const f32x4*)(h0 + BBc*HHc + e);
    union { s16x4 v; bf16 q[4]; } ua, ub;
    #pragma unroll
    for (int j=0;j<4;j++){ ua.q[j]=__float2bfloat16(a[j]); ub.q[j]=__float2bfloat16(b[j]); }
    *(f32x4*)(h0c + e) = a; *(f32x4*)(h1c + e) = b;
    *(s16x4*)(h0cb + e) = ua.v; *(s16x4*)(h1cb + e) = ub.v;
}

// h0_dec [NE][2][256][1024] -> hd0/hd1 [NE*B][H] fp32 + bf16
__global__ __launch_bounds__(256) void init_hd(const float* __restrict__ hd,
                                               float* __restrict__ hd0, float* __restrict__ hd1,
                                               bf16* __restrict__ hd0b, bf16* __restrict__ hd1b){
    const int i = blockIdx.x*256 + threadIdx.x;
    if (i >= (NEBc*HHc)/4) return;
    const int e  = i*4;
    const int hh = e & (HHc-1);
    const int r  = e >> 10;
    const int ne = r >> 8;
    const int b  = r & 255;
    f32x4 a = *(const f32x4*)(hd + (((size_t)ne*2 + 0)*BBc + b)*HHc + hh);
    f32x4 c = *(const f32x4*)(hd + (((size_t)ne*2 + 1)*BBc + b)*HHc + hh);
    union { s16x4 v; bf16 q[4]; } ua, uc;
    #pragma unroll
    for (int j=0;j<4;j++){ ua.q[j]=__float2bfloat16(a[j]); uc.q[j]=__float2bfloat16(c[j]); }
    *(f32x4*)(hd0 + e) = a; *(f32x4*)(hd1 + e) = c;
    *(s16x4*)(hd0b + e) = ua.v; *(s16x4*)(hd1b + e) = uc.v;
}

__global__ __launch_bounds__(256) void bias_tanh4(const float* __restrict__ in,
                                                  const float* __restrict__ b, bf16* __restrict__ out){
    const int i = blockIdx.x*256 + threadIdx.x;
    if (i >= (NEBc*LLc)/4) return;
    const int e = i*4;
    const int c = e & (LLc-1);
    f32x4 v = *(const f32x4*)(in + e);
    f32x4 bb = *(const f32x4*)(b + c);
    union { s16x4 s; bf16 q[4]; } u;
    #pragma unroll
    for (int j=0;j<4;j++) u.q[j] = __float2bfloat16(tanhf(v[j] + bb[j]));
    *(s16x4*)(out + e) = u.s;
}

// ---------------- host side ----------------

extern "C" void kernel_launch(void* const* d_in, const int* in_sizes, int n_in,
                              void* d_out, int out_size, void* d_ws, size_t ws_size,
                              hipStream_t stream)
{
    const float* target = (const float*)d_in[0];
    const float* latent = (const float*)d_in[1];
    const float* h0     = (const float*)d_in[2];
    const float* h0_dec = (const float*)d_in[3];
    const float* c_wih0 = (const float*)d_in[4];
    const float* c_whh0 = (const float*)d_in[5];
    const float* c_bih0 = (const float*)d_in[6];
    const float* c_bhh0 = (const float*)d_in[7];
    const float* c_wih1 = (const float*)d_in[8];
    const float* c_whh1 = (const float*)d_in[9];
    const float* c_bih1 = (const float*)d_in[10];
    const float* c_bhh1 = (const float*)d_in[11];
    const float* ce_w   = (const float*)d_in[12];
    const float* ce_b   = (const float*)d_in[13];
    const float* d_wih0 = (const float*)d_in[14];
    const float* d_whh0 = (const float*)d_in[15];
    const float* d_bih0 = (const float*)d_in[16];
    const float* d_bhh0 = (const float*)d_in[17];
    const float* d_wih1 = (const float*)d_in[18];
    const float* d_whh1 = (const float*)d_in[19];
    const float* d_bih1 = (const float*)d_in[20];
    const float* d_bhh1 = (const float*)d_in[21];
    const float* o_w    = (const float*)d_in[22];
    const float* o_b    = (const float*)d_in[23];
    float* out = (float*)d_out;

    // ---- workspace (~170 MB) ----
    float* fp = (float*)d_ws;
    auto fa = [&](size_t n){ float* q = fp; fp += n; return q; };
    float* hd0   = fa((size_t)NEBc*HHc);
    float* hd1   = fa((size_t)NEBc*HHc);
    float* h0c   = fa((size_t)BBc*HHc);
    float* h1c   = fa((size_t)BBc*HHc);
    float* emb   = fa((size_t)NEBc*LLc);
    float* bp_c0 = fa(HB*256);
    float* bp_c1 = fa(HB*256);
    float* bp_d0 = fa(HB*256);
    float* bp_d1 = fa(HB*256);

    bf16* bb = (bf16*)fp;
    auto ba = [&](size_t n){ bf16* q = bb; bb += n; return q; };
    bf16* giEb   = ba((size_t)NEBc*H3c);   // packed bf16
    bf16* gi0cb  = ba((size_t)BBc*H3c);    // packed bf16
    bf16* hd0b[2] = { ba((size_t)NEBc*HHc), ba((size_t)NEBc*HHc) };
    bf16* hd1b[2] = { ba((size_t)NEBc*HHc), ba((size_t)NEBc*HHc) };
    bf16* h0cb[2] = { ba((size_t)BBc*HHc),  ba((size_t)BBc*HHc) };
    bf16* h1cb[2] = { ba((size_t)BBc*HHc),  ba((size_t)BBc*HHc) };
    bf16* xb    = ba((size_t)SSc*NEBc*KXc);
    bf16* coutb = ba((size_t)NEBc*HHc);
    bf16* embb  = ba((size_t)NEBc*LLc);
    bf16* latb  = ba((size_t)BBc*LLc);
    bf16* Wxpk  = ba((size_t)HB*192*KXc);
    bf16* Whid0 = ba((size_t)HB*192*HHc);
    bf16* Wlod1 = ba((size_t)HB*192*HHc);
    bf16* Whid1 = ba((size_t)HB*192*HHc);
    bf16* Whic0 = ba((size_t)HB*192*HHc);
    bf16* Wloc1 = ba((size_t)HB*192*HHc);
    bf16* Whic1 = ba((size_t)HB*192*HHc);
    bf16* Epd   = ba((size_t)HB*192*LLc);
    bf16* Epc   = ba((size_t)HB*192*LLc);
    bf16* cewb  = ba((size_t)LLc*HHc);
    bf16* owb   = ba((size_t)KXc*HHc);

    auto packw = [&](const float* src, int ld, int c0, int kv, int kp, bf16* dst){
        const int tot = HB*192*kp;
        hipLaunchKernelGGL(pack_w2, dim3((tot+255)/256), dim3(256),0,stream, src,ld,c0,kv,kp,dst,tot);
    };

    // ---- setup ----
    hipLaunchKernelGGL(cvt_bf16_k, dim3((BBc*LLc/4+255)/256), dim3(256),0,stream, latent, latb, BBc*LLc/4);
    hipLaunchKernelGGL(cvt_bf16_k, dim3((LLc*HHc/4+255)/256), dim3(256),0,stream, ce_w, cewb, LLc*HHc/4);
    hipLaunchKernelGGL(pad_ow, dim3((KXc*HHc)/256), dim3(256),0,stream, o_w, owb);
    hipLaunchKernelGGL(build_xb, dim3((SSc*NEBc*KXc)/256), dim3(256),0,stream, target, xb);
    hipLaunchKernelGGL(init_hc, dim3((BBc*HHc/4)/256), dim3(256),0,stream, h0, h0c, h1c, h0cb[0], h1cb[0]);
    hipLaunchKernelGGL(init_hd, dim3((NEBc*HHc/4)/256), dim3(256),0,stream, h0_dec, hd0, hd1, hd0b[0], hd1b[0]);
    packw(d_wih0, INc+LLc, 0,   INc, KXc, Wxpk);
    packw(d_whh0, HHc,     0,   HHc, HHc, Whid0);
    packw(d_wih1, HHc,     0,   HHc, HHc, Wlod1);
    packw(d_whh1, HHc,     0,   HHc, HHc, Whid1);
    packw(c_whh0, HHc,     0,   HHc, HHc, Whic0);
    packw(c_wih1, HHc,     0,   HHc, HHc, Wloc1);
    packw(c_whh1, HHc,     0,   HHc, HHc, Whic1);
    packw(d_wih0, INc+LLc, INc, LLc, LLc, Epd);
    packw(c_wih0, LLc,     0,   LLc, LLc, Epc);
    hipLaunchKernelGGL(pack_bias, dim3((HB*256+255)/256), dim3(256),0,stream, c_bih0, c_bhh0, bp_c0);
    hipLaunchKernelGGL(pack_bias, dim3((HB*256+255)/256), dim3(256),0,stream, c_bih1, c_bhh1, bp_c1);
    hipLaunchKernelGGL(pack_bias, dim3((HB*256+255)/256), dim3(256),0,stream, d_bih0, d_bhh0, bp_d0);
    hipLaunchKernelGGL(pack_bias, dim3((HB*256+255)/256), dim3(256),0,stream, d_bih1, d_bhh1, bp_d1);

    // conductor l0 gi (loop-invariant), packed bf16
    hipLaunchKernelGGL(gemm_pack, dim3(HB, BBc/64), dim3(256),0,stream, latb, Epc, gi0cb);

    // ---- conductor: 16 sequential 2-layer fused GRU steps (M=256, BM=64) ----
    int c = 0;
    for (int s=0;s<NEc;s++){
        hipLaunchKernelGGL((gru_fused2<64>), dim3(HB, BBc/64), dim3(256),0,stream,
                           (const bf16*)nullptr, 0, 0, (const bf16*)nullptr,
                           h0cb[c], Whic0, gi0cb, bp_c0, h0c, h0cb[1-c], (bf16*)nullptr);
        hipLaunchKernelGGL((gru_fused2<64>), dim3(HB, BBc/64), dim3(256),0,stream,
                           h0cb[1-c], HHc, HHc, Wloc1,
                           h1cb[c], Whic1, (const bf16*)nullptr, bp_c1, h1c, h1cb[1-c],
                           coutb + (size_t)s*BBc*HHc);
        c ^= 1;
    }

    // ---- embedding: emb = tanh(cout @ ce_w^T + b); then packed giE = emb @ We^T ----
    hipLaunchKernelGGL((gemm_bf<128,128>), dim3(LLc/128, NEBc/128), dim3(256),0,stream,
                       coutb, cewb, emb, HHc, LLc);
    hipLaunchKernelGGL(bias_tanh4, dim3((NEBc*LLc/4)/256), dim3(256),0,stream, emb, ce_b, embb);
    hipLaunchKernelGGL(gemm_pack, dim3(HB, NEBc/64), dim3(256),0,stream, embb, Epd, giEb);

    // ---- decoder: 16 sequential 2-layer fused GRU steps (M=4096, BM=128) ----
    int d = 0;
    for (int t=0;t<SSc;t++){
        hipLaunchKernelGGL((gru_fused2<128>), dim3(HB, NEBc/128), dim3(256),0,stream,
                           xb + (size_t)t*NEBc*KXc, KXc, KXc, Wxpk,
                           hd0b[d], Whid0, giEb, bp_d0, hd0, hd0b[1-d], (bf16*)nullptr);
        hipLaunchKernelGGL((gru_fused2<128>), dim3(HB, NEBc/128), dim3(256),0,stream,
                           hd0b[1-d], HHc, HHc, Wlod1,
                           hd1b[d], Whid1, (const bf16*)nullptr, bp_d1, hd1, hd1b[1-d], (bf16*)nullptr);
        hipLaunchKernelGGL(owsm, dim3(NEBc/64), dim3(256),0,stream, hd1b[1-d], owb, o_b, out, t);
        d ^= 1;
    }
}

// Round 6
// 2788.179 us; speedup vs baseline: 2.0751x; 1.7048x over previous
//
#include <hip/hip_runtime.h>
#include <hip/hip_bf16.h>
#include <cstdint>
#include <cstddef>

#define NEc 16
#define SSc 16
#define BBc 256
#define INc 61
#define HHc 1024
#define LLc 512
#define H3c 3072
#define NEBc 4096   // NE*B
#define KXc 64      // x width padded 61->64
#define HB  16      // h-blocks of 64

typedef __hip_bfloat16 bf16;
typedef __attribute__((ext_vector_type(8))) short bf16x8;   // 8 bf16 = 4 VGPR (MFMA A/B frag)
typedef __attribute__((ext_vector_type(4))) float f32x4;    // MFMA C/D frag
typedef __attribute__((ext_vector_type(4))) short s16x4;    // 4 bf16 packed store

__device__ __forceinline__ void gload16(const void* g, void* l){
    __builtin_amdgcn_global_load_lds((const __attribute__((address_space(1))) unsigned int*)g,
                                     (__attribute__((address_space(3))) unsigned int*)l, 16, 0, 0);
}

__device__ __forceinline__ float sigmoidf_(float x){ return 1.0f/(1.0f+__expf(-x)); }

// One work-slice for the multi-role fused kernel.
// mode: -1 = inactive, 0 = fused GRU cell, 1 = output-projection+softmax.
// GRU: pre-act = A0@Wlo[0:K0] + A1@Wlo[K0:K0+K1] + A2@Whi (r,z always; 'in'
// from the lo phases, 'hn' from the hi phase), then full gate math in-register.
// OWSM: A0 = h bf16, Wlo = o_w padded [64][1024], bp = o_b, h = out, K0 = t.
struct Slice {
    const bf16* A0; int lda0; int K0;
    const bf16* A1; int lda1; int K1;
    const bf16* A2; int lda2;
    const bf16* Wlo;
    const bf16* Whi;
    const float* bp;
    float* h;
    bf16* hbout;
    bf16* out2;
    int mode;
};

// ---------------------------------------------------------------------------
// Fused GRU body. Packed weight layout per hb (64 h-cols): 192 B-rows,
// row c: g=c>>4, hsub=g/3, gate=g%3 (r,z,n), h-col = hb*64+hsub*16+(c&15).
// Wave (wm,wc): wm = row half, wc = hsub pair. Same lane holds r,z,in,hn of
// one h element -> pure-register epilogue (no LDS exchange, balanced MFMAs).
// ---------------------------------------------------------------------------
template<int BM>
__device__ void gru_body(const Slice& s, char* smem)
{
    constexpr int MR = BM/32;
    char* sA = smem;
    char* sB = smem + BM*128;

    const int tid  = threadIdx.x;
    const int lane = tid & 63;
    const int wave = tid >> 6;
    const int wm   = wave >> 1;
    const int wc   = wave & 1;
    const int lr   = lane & 15;
    const int lk   = lane >> 4;
    const int hb   = blockIdx.x;
    const int m0   = blockIdx.y * BM;

    const int Klo = s.K0 + s.K1;
    const bf16* WloB = s.Wlo + (size_t)hb*192*Klo;
    const bf16* WhiB = s.Whi + (size_t)hb*192*1024;

    f32x4 acc[MR][2][4];                        // [mi][hsub-local][r,z,in,hn]
    #pragma unroll
    for (int mi=0;mi<MR;mi++)
      #pragma unroll
      for (int hs=0;hs<2;hs++)
        #pragma unroll
        for (int g=0;g<4;g++)
          #pragma unroll
          for (int j=0;j<4;j++) acc[mi][hs][g][j] = 0.f;

    bool first = true;

    // ---- lo phases: r,z,'in' over A0 (K0) then A1 (K1), weights Wlo ----
    for (int k0 = 0; k0 < Klo; k0 += 64){
        if (!first) __syncthreads();
        first = false;
        const bf16* Ab; int lda, ac0;
        if (k0 < s.K0){ Ab = s.A0; lda = s.lda0; ac0 = k0; }
        else          { Ab = s.A1; lda = s.lda1; ac0 = k0 - s.K0; }
        #pragma unroll
        for (int i=0;i<MR;i++){
            const int o = i*4096 + tid*16;
            const int u = o ^ (((o>>7)&7)<<4);
            gload16(Ab + (size_t)(m0 + (u>>7))*lda + ac0 + ((u&127)>>1), sA + o);
        }
        #pragma unroll
        for (int i=0;i<6;i++){
            const int o = i*4096 + tid*16;
            const int u = o ^ (((o>>7)&7)<<4);
            gload16(WloB + (size_t)(u>>7)*Klo + k0 + ((u&127)>>1), sB + o);
        }
        __syncthreads();
        #pragma unroll
        for (int ks=0;ks<2;ks++){
            bf16x8 av[MR];
            #pragma unroll
            for (int mi=0;mi<MR;mi++){
                const int r = wm*(BM/2) + mi*16 + lr;
                const int u = r*128 + ks*64 + lk*16;
                av[mi] = *(const bf16x8*)(sA + (u ^ ((r&7)<<4)));
            }
            #pragma unroll
            for (int hs=0;hs<2;hs++)
              #pragma unroll
              for (int g3=0;g3<3;g3++){
                const int br = ((wc*2+hs)*3 + g3)*16 + lr;
                const int u  = br*128 + ks*64 + lk*16;
                const bf16x8 bv = *(const bf16x8*)(sB + (u ^ ((br&7)<<4)));
                if (g3==0){
                    #pragma unroll
                    for (int mi=0;mi<MR;mi++)
                        acc[mi][hs][0] = __builtin_amdgcn_mfma_f32_16x16x32_bf16(av[mi], bv, acc[mi][hs][0], 0,0,0);
                } else if (g3==1){
                    #pragma unroll
                    for (int mi=0;mi<MR;mi++)
                        acc[mi][hs][1] = __builtin_amdgcn_mfma_f32_16x16x32_bf16(av[mi], bv, acc[mi][hs][1], 0,0,0);
                } else {
                    #pragma unroll
                    for (int mi=0;mi<MR;mi++)
                        acc[mi][hs][2] = __builtin_amdgcn_mfma_f32_16x16x32_bf16(av[mi], bv, acc[mi][hs][2], 0,0,0);
                }
              }
        }
    }

    // ---- hi phase: r,z,'hn' over A2 (K=1024), weights Whi ----
    for (int k0 = 0; k0 < 1024; k0 += 64){
        if (!first) __syncthreads();
        first = false;
        #pragma unroll
        for (int i=0;i<MR;i++){
            const int o = i*4096 + tid*16;
            const int u = o ^ (((o>>7)&7)<<4);
            gload16(s.A2 + (size_t)(m0 + (u>>7))*s.lda2 + k0 + ((u&127)>>1), sA + o);
        }
        #pragma unroll
        for (int i=0;i<6;i++){
            const int o = i*4096 + tid*16;
            const int u = o ^ (((o>>7)&7)<<4);
            gload16(WhiB + (size_t)(u>>7)*1024 + k0 + ((u&127)>>1), sB + o);
        }
        __syncthreads();
        #pragma unroll
        for (int ks=0;ks<2;ks++){
            bf16x8 av[MR];
            #pragma unroll
            for (int mi=0;mi<MR;mi++){
                const int r = wm*(BM/2) + mi*16 + lr;
                const int u = r*128 + ks*64 + lk*16;
                av[mi] = *(const bf16x8*)(sA + (u ^ ((r&7)<<4)));
            }
            #pragma unroll
            for (int hs=0;hs<2;hs++)
              #pragma unroll
              for (int g3=0;g3<3;g3++){
                const int br = ((wc*2+hs)*3 + g3)*16 + lr;
                const int u  = br*128 + ks*64 + lk*16;
                const bf16x8 bv = *(const bf16x8*)(sB + (u ^ ((br&7)<<4)));
                if (g3==0){
                    #pragma unroll
                    for (int mi=0;mi<MR;mi++)
                        acc[mi][hs][0] = __builtin_amdgcn_mfma_f32_16x16x32_bf16(av[mi], bv, acc[mi][hs][0], 0,0,0);
                } else if (g3==1){
                    #pragma unroll
                    for (int mi=0;mi<MR;mi++)
                        acc[mi][hs][1] = __builtin_amdgcn_mfma_f32_16x16x32_bf16(av[mi], bv, acc[mi][hs][1], 0,0,0);
                } else {
                    #pragma unroll
                    for (int mi=0;mi<MR;mi++)
                        acc[mi][hs][3] = __builtin_amdgcn_mfma_f32_16x16x32_bf16(av[mi], bv, acc[mi][hs][3], 0,0,0);
                }
              }
        }
    }

    // ---- pure-register epilogue ----
    #pragma unroll
    for (int hs=0;hs<2;hs++){
        const int hsub = wc*2 + hs;
        const int hc   = hb*64 + hsub*16 + lr;
        const float bpr  = s.bp[hb*256 +       hsub*16 + lr];
        const float bpz  = s.bp[hb*256 +  64 + hsub*16 + lr];
        const float bpin = s.bp[hb*256 + 128 + hsub*16 + lr];
        const float bphn = s.bp[hb*256 + 192 + hsub*16 + lr];
        #pragma unroll
        for (int mi=0;mi<MR;mi++)
          #pragma unroll
          for (int j=0;j<4;j++){
            const int rl = wm*(BM/2) + mi*16 + lk*4 + j;   // C/D: row=(lane>>4)*4+j
            const int m  = m0 + rl;
            const float r = sigmoidf_(acc[mi][hs][0][j] + bpr);
            const float z = sigmoidf_(acc[mi][hs][1][j] + bpz);
            const float n = tanhf(acc[mi][hs][2][j] + bpin + r*(acc[mi][hs][3][j] + bphn));
            const size_t off = (size_t)m*HHc + hc;
            const float hnew = (1.f - z)*n + z*s.h[off];
            s.h[off] = hnew;
            const bf16 hb16 = __float2bfloat16(hnew);
            s.hbout[off] = hb16;
            if (s.out2) s.out2[off] = hb16;
          }
    }
}

// ---------------------------------------------------------------------------
// Output projection + softmax body (64 rows per active block, x==0 plane).
// logits = A0 @ Wlo(o_w padded)^T + bp(o_b); softmax over 61; scatter to out.
// ---------------------------------------------------------------------------
__device__ void owsm_body(const Slice& s, char* smem)
{
    if (blockIdx.x != 0) return;
    char* sA = smem; char* sB = smem + 8192;
    float* lg = (float*)(smem + 16384);        // [64][68]
    const int tid  = threadIdx.x;
    const int lane = tid & 63;
    const int wave = tid >> 6;
    const int wm   = wave >> 1;
    const int wc   = wave & 1;
    const int lr   = lane & 15;
    const int lk   = lane >> 4;
    const int m0   = blockIdx.y * 64;
    const int t    = s.K0;

    f32x4 acc[2][2];
    #pragma unroll
    for (int mi=0;mi<2;mi++)
      #pragma unroll
      for (int ni=0;ni<2;ni++)
        #pragma unroll
        for (int j=0;j<4;j++) acc[mi][ni][j]=0.f;

    for (int k0=0;k0<1024;k0+=64){
        if (k0) __syncthreads();
        #pragma unroll
        for (int i=0;i<2;i++){
            const int o = i*4096 + tid*16;
            const int u = o ^ (((o>>7)&7)<<4);
            gload16(s.A0 + (size_t)(m0 + (u>>7))*1024 + k0 + ((u&127)>>1), sA + o);
        }
        #pragma unroll
        for (int i=0;i<2;i++){
            const int o = i*4096 + tid*16;
            const int u = o ^ (((o>>7)&7)<<4);
            gload16(s.Wlo + (size_t)(u>>7)*1024 + k0 + ((u&127)>>1), sB + o);
        }
        __syncthreads();
        #pragma unroll
        for (int ks=0;ks<2;ks++){
            bf16x8 av[2], bv[2];
            #pragma unroll
            for (int mi=0;mi<2;mi++){
                const int r = wm*32 + mi*16 + lr;
                const int u = r*128 + ks*64 + lk*16;
                av[mi] = *(const bf16x8*)(sA + (u ^ ((r&7)<<4)));
            }
            #pragma unroll
            for (int ni=0;ni<2;ni++){
                const int r = wc*32 + ni*16 + lr;
                const int u = r*128 + ks*64 + lk*16;
                bv[ni] = *(const bf16x8*)(sB + (u ^ ((r&7)<<4)));
            }
            #pragma unroll
            for (int mi=0;mi<2;mi++)
              #pragma unroll
              for (int ni=0;ni<2;ni++)
                acc[mi][ni] = __builtin_amdgcn_mfma_f32_16x16x32_bf16(av[mi], bv[ni], acc[mi][ni], 0,0,0);
        }
    }
    #pragma unroll
    for (int mi=0;mi<2;mi++)
      #pragma unroll
      for (int ni=0;ni<2;ni++)
        #pragma unroll
        for (int j=0;j<4;j++){
            const int rl = wm*32 + mi*16 + lk*4 + j;
            const int c  = wc*32 + ni*16 + lr;
            lg[rl*68 + c] = (c < INc) ? (acc[mi][ni][j] + s.bp[c]) : -1e30f;
        }
    __syncthreads();
    const int row = tid >> 2;
    const int q   = tid & 3;
    float mx = -1e30f;
    #pragma unroll
    for (int i=0;i<16;i++) mx = fmaxf(mx, lg[row*68 + q*16+i]);
    mx = fmaxf(mx, __shfl_xor(mx,1));
    mx = fmaxf(mx, __shfl_xor(mx,2));
    float ev[16];
    float sum = 0.f;
    #pragma unroll
    for (int i=0;i<16;i++){ ev[i] = __expf(lg[row*68 + q*16+i] - mx); sum += ev[i]; }
    sum += __shfl_xor(sum,1);
    sum += __shfl_xor(sum,2);
    const float inv = 1.f/sum;
    const int R = m0 + row;
    const int ne = R >> 8, b = R & 255;
    float* op = s.h + ((size_t)((ne*SSc + t)*BBc + b))*INc;
    #pragma unroll
    for (int i=0;i<16;i++){
        const int c = q*16 + i;
        if (c < INc) op[c] = ev[i]*inv;
    }
}

// ---------------------------------------------------------------------------
// Multi-role fused step kernel: one independent Slice per blockIdx.z.
// ---------------------------------------------------------------------------
template<int BM>
__global__ __launch_bounds__(256)
void fused_step(Slice s0, Slice s1, Slice s2)
{
    constexpr int SMEMSZ = (BM==64) ? (16384 + 64*68*4) : (BM+192)*128;
    __shared__ char smem[SMEMSZ];
    const Slice& s = (blockIdx.z==0) ? s0 : (blockIdx.z==1) ? s1 : s2;
    if (s.mode < 0) return;
    if constexpr (BM==64){
        if (s.mode == 1){ owsm_body(s, smem); return; }
    }
    gru_body<BM>(s, smem);
}

// ---------------------------------------------------------------------------
// plain bf16 GEMM-NT (proven): C[M,N] = A[M,K] @ B[N,K]^T, C fp32 (embedding)
// ---------------------------------------------------------------------------
template<int BM,int BN>
__global__ __launch_bounds__(256)
void gemm_bf(const bf16* __restrict__ A, const bf16* __restrict__ Bm, float* __restrict__ C,
             int K, int ldc)
{
    constexpr int WAVES_M = (BM==128) ? 2 : 1;
    constexpr int WM = BM / WAVES_M;
    constexpr int WN = BN / (4/WAVES_M);
    constexpr int MR = WM / 16;
    constexpr int NR = WN / 16;
    constexpr int ASW = (BM*128)/4096;
    constexpr int BSW = (BN*128)/4096;

    __shared__ char smem[(BM+BN)*128];
    char* sA = smem;
    char* sB = smem + BM*128;

    const int tid  = threadIdx.x;
    const int lane = tid & 63;
    const int wave = tid >> 6;
    const int wm   = (WAVES_M==2) ? (wave>>1) : 0;
    const int wn   = (WAVES_M==2) ? (wave&1)  : wave;
    const int lr   = lane & 15;
    const int lk   = lane >> 4;
    const int m0   = blockIdx.y * BM;
    const int n0   = blockIdx.x * BN;

    f32x4 acc[MR][NR];
    #pragma unroll
    for (int mi=0;mi<MR;mi++)
      #pragma unroll
      for (int ni=0;ni<NR;ni++)
        #pragma unroll
        for (int j=0;j<4;j++) acc[mi][ni][j] = 0.f;

    for (int k0 = 0; k0 < K; k0 += 64){
        if (k0) __syncthreads();
        #pragma unroll
        for (int i=0;i<ASW;i++){
            const int o = i*4096 + tid*16;
            const int u = o ^ (((o>>7)&7)<<4);
            gload16(A + (size_t)(m0 + (u>>7))*K + k0 + ((u&127)>>1), sA + o);
        }
        #pragma unroll
        for (int i=0;i<BSW;i++){
            const int o = i*4096 + tid*16;
            const int u = o ^ (((o>>7)&7)<<4);
            gload16(Bm + (size_t)(n0 + (u>>7))*K + k0 + ((u&127)>>1), sB + o);
        }
        __syncthreads();
        #pragma unroll
        for (int ks=0;ks<2;ks++){
            bf16x8 av[MR], bv[NR];
            #pragma unroll
            for (int mi=0;mi<MR;mi++){
                const int r = wm*WM + mi*16 + lr;
                const int u = r*128 + ks*64 + lk*16;
                av[mi] = *(const bf16x8*)(sA + (u ^ ((r&7)<<4)));
            }
            #pragma unroll
            for (int ni=0;ni<NR;ni++){
                const int r = wn*WN + ni*16 + lr;
                const int u = r*128 + ks*64 + lk*16;
                bv[ni] = *(const bf16x8*)(sB + (u ^ ((r&7)<<4)));
            }
            #pragma unroll
            for (int mi=0;mi<MR;mi++)
              #pragma unroll
              for (int ni=0;ni<NR;ni++)
                acc[mi][ni] = __builtin_amdgcn_mfma_f32_16x16x32_bf16(av[mi], bv[ni], acc[mi][ni], 0,0,0);
        }
    }
    #pragma unroll
    for (int mi=0;mi<MR;mi++)
      #pragma unroll
      for (int ni=0;ni<NR;ni++)
        #pragma unroll
        for (int j=0;j<4;j++){
            const int r = m0 + wm*WM + mi*16 + lk*4 + j;
            const int c = n0 + wn*WN + ni*16 + lr;
            C[(size_t)r*ldc + c] = acc[mi][ni][j];
        }
}

// ---------------------------------------------------------------------------
// setup kernels
// ---------------------------------------------------------------------------
// gate-interleaved packing with dst column window:
// dst[hb][c][dstc0 + k] (dst row-ld dstld); c: g=c>>4, hsub=g/3, gate=g%3,
// src row = gate*1024 + hb*64 + hsub*16 + (c&15), col = col0+k (0 if k>=Kvalid)
__global__ __launch_bounds__(256) void pack_w2(const float* __restrict__ src, int srcld,
                                               int col0, int Kvalid, int Kchunk,
                                               bf16* __restrict__ dst, int dstld, int dstc0,
                                               int total){
    const int idx = blockIdx.x*256 + threadIdx.x;
    if (idx >= total) return;
    const int k  = idx % Kchunk;
    const int c  = (idx / Kchunk) % 192;
    const int hb = idx / (Kchunk*192);
    const int g  = c >> 4;
    const int hsub = g/3;
    const int gate = g - hsub*3;
    const int row = gate*HHc + hb*64 + hsub*16 + (c & 15);
    const float v = (k < Kvalid) ? src[(size_t)row*srcld + col0 + k] : 0.f;
    dst[((size_t)hb*192 + c)*dstld + dstc0 + k] = __float2bfloat16(v);
}

// bp[hb][256] = [bih_r+bhh_r][bih_z+bhh_z][bih_n][bhh_n], within-64 = h offset
__global__ __launch_bounds__(256) void pack_bias(const float* __restrict__ bih,
                                                 const float* __restrict__ bhh,
                                                 float* __restrict__ bp){
    const int idx = blockIdx.x*256 + threadIdx.x;
    if (idx >= HB*256) return;
    const int c  = idx & 255;
    const int hb = idx >> 8;
    const int i  = hb*64 + (c&63);
    const int g  = c >> 6;
    float v;
    if      (g==0) v = bih[i] + bhh[i];
    else if (g==1) v = bih[HHc+i] + bhh[HHc+i];
    else if (g==2) v = bih[2*HHc+i];
    else           v = bhh[2*HHc+i];
    bp[idx] = v;
}

__global__ __launch_bounds__(256) void cvt_bf16_k(const float* __restrict__ in, bf16* __restrict__ out, int n4){
    const int i = blockIdx.x*256 + threadIdx.x;
    if (i >= n4) return;
    const f32x4 v = *(const f32x4*)(in + (size_t)i*4);
    union { s16x4 s; bf16 b[4]; } u;
    #pragma unroll
    for (int j=0;j<4;j++) u.b[j] = __float2bfloat16(v[j]);
    *(s16x4*)(out + (size_t)i*4) = u.s;
}

// o_w [61][1024] -> owb [64][1024] zero-padded rows
__global__ __launch_bounds__(256) void pad_ow(const float* __restrict__ w, bf16* __restrict__ o){
    const int idx = blockIdx.x*256 + threadIdx.x;
    if (idx >= KXc*HHc) return;
    const int r = idx >> 10;
    o[idx] = __float2bfloat16(r < INc ? w[(size_t)r*HHc + (idx & (HHc-1))] : 0.f);
}

// target [NE*S][B][61] -> xb bf16 [S][NE*B][64] zero-padded
__global__ __launch_bounds__(256) void build_xb(const float* __restrict__ t, bf16* __restrict__ xb){
    const int idx = blockIdx.x*256 + threadIdx.x;
    if (idx >= SSc*NEBc*KXc) return;
    const int c  = idx & 63;
    const int rr = idx >> 6;
    const int s  = rr >> 12;
    const int r  = rr & 4095;
    const int ne = r >> 8;
    const int b  = r & 255;
    const float v = (c < INc) ? t[(((size_t)(ne*SSc + s)*BBc + b)*INc) + c] : 0.f;
    xb[idx] = __float2bfloat16(v);
}

// h0 [2][256][1024] -> h0c/h1c fp32 + bf16 shadows
__global__ __launch_bounds__(256) void init_hc(const float* __restrict__ h0,
                                               float* __restrict__ h0c, float* __restrict__ h1c,
                                               bf16* __restrict__ h0cb, bf16* __restrict__ h1cb){
    const int i = blockIdx.x*256 + threadIdx.x;
    if (i >= (BBc*HHc)/4) return;
    const int e = i*4;
    f32x4 a = *(const f32x4*)(h0 + e);
    f32x4 b = *(const f32x4*)(h0 + BBc*HHc + e);
    union { s16x4 v; bf16 q[4]; } ua, ub;
    #pragma unroll
    for (int j=0;j<4;j++){ ua.q[j]=__float2bfloat16(a[j]); ub.q[j]=__float2bfloat16(b[j]); }
    *(f32x4*)(h0c + e) = a; *(f32x4*)(h1c + e) = b;
    *(s16x4*)(h0cb + e) = ua.v; *(s16x4*)(h1cb + e) = ub.v;
}

// h0_dec [NE][2][256][1024] -> hd0/hd1 [NE*B][H] fp32 + bf16
__global__ __launch_bounds__(256) void init_hd(const float* __restrict__ hd,
                                               float* __restrict__ hd0, float* __restrict__ hd1,
                                               bf16* __restrict__ hd0b, bf16* __restrict__ hd1b){
    const int i = blockIdx.x*256 + threadIdx.x;
    if (i >= (NEBc*HHc)/4) return;
    const int e  = i*4;
    const int hh = e & (HHc-1);
    const int r  = e >> 10;
    const int ne = r >> 8;
    const int b  = r & 255;
    f32x4 a = *(const f32x4*)(hd + (((size_t)ne*2 + 0)*BBc + b)*HHc + hh);
    f32x4 c = *(const f32x4*)(hd + (((size_t)ne*2 + 1)*BBc + b)*HHc + hh);
    union { s16x4 v; bf16 q[4]; } ua, uc;
    #pragma unroll
    for (int j=0;j<4;j++){ ua.q[j]=__float2bfloat16(a[j]); uc.q[j]=__float2bfloat16(c[j]); }
    *(f32x4*)(hd0 + e) = a; *(f32x4*)(hd1 + e) = c;
    *(s16x4*)(hd0b + e) = ua.v; *(s16x4*)(hd1b + e) = uc.v;
}

__global__ __launch_bounds__(256) void bias_tanh4(const float* __restrict__ in,
                                                  const float* __restrict__ b, bf16* __restrict__ out){
    const int i = blockIdx.x*256 + threadIdx.x;
    if (i >= (NEBc*LLc)/4) return;
    const int e = i*4;
    const int c = e & (LLc-1);
    f32x4 v = *(const f32x4*)(in + e);
    f32x4 bb = *(const f32x4*)(b + c);
    union { s16x4 s; bf16 q[4]; } u;
    #pragma unroll
    for (int j=0;j<4;j++) u.q[j] = __float2bfloat16(tanhf(v[j] + bb[j]));
    *(s16x4*)(out + e) = u.s;
}

// ---------------- host side ----------------

extern "C" void kernel_launch(void* const* d_in, const int* in_sizes, int n_in,
                              void* d_out, int out_size, void* d_ws, size_t ws_size,
                              hipStream_t stream)
{
    const float* target = (const float*)d_in[0];
    const float* latent = (const float*)d_in[1];
    const float* h0     = (const float*)d_in[2];
    const float* h0_dec = (const float*)d_in[3];
    const float* c_wih0 = (const float*)d_in[4];
    const float* c_whh0 = (const float*)d_in[5];
    const float* c_bih0 = (const float*)d_in[6];
    const float* c_bhh0 = (const float*)d_in[7];
    const float* c_wih1 = (const float*)d_in[8];
    const float* c_whh1 = (const float*)d_in[9];
    const float* c_bih1 = (const float*)d_in[10];
    const float* c_bhh1 = (const float*)d_in[11];
    const float* ce_w   = (const float*)d_in[12];
    const float* ce_b   = (const float*)d_in[13];
    const float* d_wih0 = (const float*)d_in[14];
    const float* d_whh0 = (const float*)d_in[15];
    const float* d_bih0 = (const float*)d_in[16];
    const float* d_bhh0 = (const float*)d_in[17];
    const float* d_wih1 = (const float*)d_in[18];
    const float* d_whh1 = (const float*)d_in[19];
    const float* d_bih1 = (const float*)d_in[20];
    const float* d_bhh1 = (const float*)d_in[21];
    const float* o_w    = (const float*)d_in[22];
    const float* o_b    = (const float*)d_in[23];
    float* out = (float*)d_out;

    // ---- workspace ----
    float* fp = (float*)d_ws;
    auto fa = [&](size_t n){ float* q = fp; fp += n; return q; };
    float* hd0   = fa((size_t)NEBc*HHc);
    float* hd1   = fa((size_t)NEBc*HHc);
    float* h0c   = fa((size_t)BBc*HHc);
    float* h1c   = fa((size_t)BBc*HHc);
    float* emb   = fa((size_t)NEBc*LLc);
    float* bp_c0 = fa(HB*256);
    float* bp_c1 = fa(HB*256);
    float* bp_d0 = fa(HB*256);
    float* bp_d1 = fa(HB*256);

    bf16* bbp = (bf16*)fp;
    auto ba = [&](size_t n){ bf16* q = bbp; bbp += n; return q; };
    bf16* hd0b[2] = { ba((size_t)NEBc*HHc), ba((size_t)NEBc*HHc) };
    bf16* hd1b[2] = { ba((size_t)NEBc*HHc), ba((size_t)NEBc*HHc) };
    bf16* h0cb[2] = { ba((size_t)BBc*HHc),  ba((size_t)BBc*HHc) };
    bf16* h1cb[2] = { ba((size_t)BBc*HHc),  ba((size_t)BBc*HHc) };
    bf16* xb     = ba((size_t)SSc*NEBc*KXc);
    bf16* coutb  = ba((size_t)NEBc*HHc);
    bf16* embb   = ba((size_t)NEBc*LLc);
    bf16* latb   = ba((size_t)BBc*LLc);
    bf16* Wloc0  = ba((size_t)HB*192*LLc);      // conductor l0: latent phase (K=512)
    bf16* Whic0  = ba((size_t)HB*192*HHc);
    bf16* Wloc1  = ba((size_t)HB*192*HHc);
    bf16* Whic1  = ba((size_t)HB*192*HHc);
    bf16* Wlod0f = ba((size_t)HB*192*576);      // decoder l0: [x(64) | emb(512)]
    bf16* Whid0  = ba((size_t)HB*192*HHc);
    bf16* Wlod1  = ba((size_t)HB*192*HHc);
    bf16* Whid1  = ba((size_t)HB*192*HHc);
    bf16* cewb   = ba((size_t)LLc*HHc);
    bf16* owb    = ba((size_t)KXc*HHc);

    auto packw = [&](const float* src, int srcld, int col0, int kv, int kchunk,
                     bf16* dst, int dstld, int dstc0){
        const int tot = HB*192*kchunk;
        hipLaunchKernelGGL(pack_w2, dim3((tot+255)/256), dim3(256),0,stream,
                           src,srcld,col0,kv,kchunk,dst,dstld,dstc0,tot);
    };

    // ---- setup ----
    hipLaunchKernelGGL(cvt_bf16_k, dim3((BBc*LLc/4+255)/256), dim3(256),0,stream, latent, latb, BBc*LLc/4);
    hipLaunchKernelGGL(cvt_bf16_k, dim3((LLc*HHc/4+255)/256), dim3(256),0,stream, ce_w, cewb, LLc*HHc/4);
    hipLaunchKernelGGL(pad_ow, dim3((KXc*HHc)/256), dim3(256),0,stream, o_w, owb);
    hipLaunchKernelGGL(build_xb, dim3((SSc*NEBc*KXc)/256), dim3(256),0,stream, target, xb);
    hipLaunchKernelGGL(init_hc, dim3((BBc*HHc/4)/256), dim3(256),0,stream, h0, h0c, h1c, h0cb[0], h1cb[0]);
    hipLaunchKernelGGL(init_hd, dim3((NEBc*HHc/4)/256), dim3(256),0,stream, h0_dec, hd0, hd1, hd0b[0], hd1b[0]);
    packw(c_wih0, LLc,     0,   LLc, LLc,  Wloc0, LLc, 0);
    packw(c_whh0, HHc,     0,   HHc, HHc,  Whic0, HHc, 0);
    packw(c_wih1, HHc,     0,   HHc, HHc,  Wloc1, HHc, 0);
    packw(c_whh1, HHc,     0,   HHc, HHc,  Whic1, HHc, 0);
    packw(d_wih0, INc+LLc, 0,   INc, KXc,  Wlod0f, 576, 0);
    packw(d_wih0, INc+LLc, INc, LLc, LLc,  Wlod0f, 576, KXc);
    packw(d_whh0, HHc,     0,   HHc, HHc,  Whid0, HHc, 0);
    packw(d_wih1, HHc,     0,   HHc, HHc,  Wlod1, HHc, 0);
    packw(d_whh1, HHc,     0,   HHc, HHc,  Whid1, HHc, 0);
    hipLaunchKernelGGL(pack_bias, dim3((HB*256+255)/256), dim3(256),0,stream, c_bih0, c_bhh0, bp_c0);
    hipLaunchKernelGGL(pack_bias, dim3((HB*256+255)/256), dim3(256),0,stream, c_bih1, c_bhh1, bp_c1);
    hipLaunchKernelGGL(pack_bias, dim3((HB*256+255)/256), dim3(256),0,stream, d_bih0, d_bhh0, bp_d0);
    hipLaunchKernelGGL(pack_bias, dim3((HB*256+255)/256), dim3(256),0,stream, d_bih1, d_bhh1, bp_d1);

    // ---- slice builders (host) ----
    auto CL0 = [&](int s){ Slice x{}; x.mode=0;
        x.A0=latb; x.lda0=LLc; x.K0=LLc; x.A1=nullptr; x.lda1=0; x.K1=0;
        x.A2=h0cb[s&1]; x.lda2=HHc; x.Wlo=Wloc0; x.Whi=Whic0; x.bp=bp_c0;
        x.h=h0c; x.hbout=h0cb[(s+1)&1]; x.out2=nullptr; return x; };
    auto CL1 = [&](int s){ Slice x{}; x.mode=0;
        x.A0=h0cb[(s+1)&1]; x.lda0=HHc; x.K0=HHc; x.A1=nullptr; x.lda1=0; x.K1=0;
        x.A2=h1cb[s&1]; x.lda2=HHc; x.Wlo=Wloc1; x.Whi=Whic1; x.bp=bp_c1;
        x.h=h1c; x.hbout=h1cb[(s+1)&1]; x.out2=coutb + (size_t)s*BBc*HHc; return x; };
    auto DL0 = [&](int t){ Slice x{}; x.mode=0;
        x.A0=xb + (size_t)t*NEBc*KXc; x.lda0=KXc; x.K0=KXc;
        x.A1=embb; x.lda1=LLc; x.K1=LLc;
        x.A2=hd0b[t&1]; x.lda2=HHc; x.Wlo=Wlod0f; x.Whi=Whid0; x.bp=bp_d0;
        x.h=hd0; x.hbout=hd0b[(t+1)&1]; x.out2=nullptr; return x; };
    auto DL1 = [&](int t){ Slice x{}; x.mode=0;
        x.A0=hd0b[(t+1)&1]; x.lda0=HHc; x.K0=HHc; x.A1=nullptr; x.lda1=0; x.K1=0;
        x.A2=hd1b[t&1]; x.lda2=HHc; x.Wlo=Wlod1; x.Whi=Whid1; x.bp=bp_d1;
        x.h=hd1; x.hbout=hd1b[(t+1)&1]; x.out2=nullptr; return x; };
    auto OW = [&](int t){ Slice x{}; x.mode=1;
        x.A0=hd1b[(t+1)&1]; x.K0=t; x.Wlo=owb; x.bp=o_b; x.h=out; return x; };
    Slice NS{}; NS.mode = -1;

    // ---- conductor: C_init + 16 combined steps ----
    hipLaunchKernelGGL((fused_step<32>), dim3(HB, BBc/32, 1), dim3(256),0,stream, CL0(0), NS, NS);
    for (int s=0;s<NEc;s++){
        if (s < NEc-1)
            hipLaunchKernelGGL((fused_step<32>), dim3(HB, BBc/32, 2), dim3(256),0,stream,
                               CL1(s), CL0(s+1), NS);
        else
            hipLaunchKernelGGL((fused_step<32>), dim3(HB, BBc/32, 1), dim3(256),0,stream,
                               CL1(s), NS, NS);
    }

    // ---- embedding: emb = tanh(cout @ ce_w^T + b) -> bf16 ----
    hipLaunchKernelGGL((gemm_bf<64,128>), dim3(LLc/128, NEBc/64), dim3(256),0,stream,
                       coutb, cewb, emb, HHc, LLc);
    hipLaunchKernelGGL(bias_tanh4, dim3((NEBc*LLc/4)/256), dim3(256),0,stream, emb, ce_b, embb);

    // ---- decoder: D_init + 16 combined steps + final softmax ----
    hipLaunchKernelGGL((fused_step<64>), dim3(HB, NEBc/64, 1), dim3(256),0,stream, DL0(0), NS, NS);
    for (int t=0;t<SSc;t++){
        Slice s1 = (t < SSc-1) ? DL0(t+1) : NS;
        Slice s2 = (t >= 1) ? OW(t-1) : NS;
        const int nz = (t >= 1) ? 3 : 2;
        hipLaunchKernelGGL((fused_step<64>), dim3(HB, NEBc/64, nz), dim3(256),0,stream,
                           DL1(t), s1, s2);
    }
    hipLaunchKernelGGL((fused_step<64>), dim3(1, NEBc/64, 1), dim3(256),0,stream, OW(SSc-1), NS, NS);
}